// Round 1
// baseline (2684.812 us; speedup 1.0000x reference)
//
#include <hip/hip_runtime.h>
#include <math.h>

#define BH 32
#define N_ 4096
#define D_ 64
#define M_ 256
#define L_ 16
#define DIM_ 512
#define K3_ 1536

// ---------- reduction helpers (256-thread blocks) ----------
__device__ inline float wave_sum(float v){
  #pragma unroll
  for (int o=32;o;o>>=1) v += __shfl_down(v,o,64);
  return v;
}
__device__ inline float wave_max(float v){
  #pragma unroll
  for (int o=32;o;o>>=1) v = fmaxf(v,__shfl_down(v,o,64));
  return v;
}
__device__ inline float blk_sum256(float v, float* sm){
  v = wave_sum(v);
  int lane = threadIdx.x & 63, wid = threadIdx.x >> 6;
  if (lane==0) sm[wid]=v;
  __syncthreads();
  float r = sm[0]+sm[1]+sm[2]+sm[3];
  __syncthreads();
  return r;
}
__device__ inline float blk_max256(float v, float* sm){
  v = wave_max(v);
  int lane = threadIdx.x & 63, wid = threadIdx.x >> 6;
  if (lane==0) sm[wid]=v;
  __syncthreads();
  float r = fmaxf(fmaxf(sm[0],sm[1]),fmaxf(sm[2],sm[3]));
  __syncthreads();
  return r;
}

// ---------- 1. LayerNorm: 1 block per row of 512 ----------
__global__ __launch_bounds__(256) void ln_k(const float* __restrict__ x,
    const float* __restrict__ g, const float* __restrict__ bt, float* __restrict__ xn){
  int row = blockIdx.x, t = threadIdx.x;
  __shared__ float sm[4];
  const float* xr = x + (size_t)row*DIM_;
  float v0 = xr[t], v1 = xr[t+256];
  float mu = blk_sum256(v0+v1, sm) * (1.f/DIM_);
  float d0 = v0-mu, d1 = v1-mu;
  float var = blk_sum256(d0*d0+d1*d1, sm) * (1.f/DIM_);
  float rs = rsqrtf(var + 1e-5f);
  float* xo = xn + (size_t)row*DIM_;
  xo[t]     = d0*rs*g[t]     + bt[t];
  xo[t+256] = d1*rs*g[t+256] + bt[t+256];
}

// ---------- 2. QKV GEMM: [16384,512]@[512,1536], scatter to q,k,v [B,H,N,D] ----------
__global__ __launch_bounds__(256) void gemm_qkv_k(const float* __restrict__ A,
    const float* __restrict__ Bm, float* __restrict__ q, float* __restrict__ k,
    float* __restrict__ v){
  __shared__ float As[16][68];
  __shared__ float Bs[16][66];
  int t = threadIdx.x, tx = t & 15, ty = t >> 4;
  int row0 = blockIdx.y*64, col0 = blockIdx.x*64;
  float acc[4][4];
  #pragma unroll
  for (int i=0;i<4;i++){
    #pragma unroll
    for (int j=0;j<4;j++) acc[i][j]=0.f;
  }
  for (int k0=0;k0<DIM_;k0+=16){
    __syncthreads();
    #pragma unroll
    for (int it=0;it<4;it++){
      int flat = t + it*256;
      int ka = flat & 15, m = flat >> 4;
      As[ka][m] = A[(size_t)(row0+m)*DIM_ + (k0+ka)];
      int nn = flat & 63, kb = flat >> 6;
      Bs[kb][nn] = Bm[(size_t)(k0+kb)*K3_ + (col0+nn)];
    }
    __syncthreads();
    #pragma unroll
    for (int kk=0;kk<16;kk++){
      float a[4], b[4];
      #pragma unroll
      for (int i=0;i<4;i++) a[i]=As[kk][ty*4+i];
      #pragma unroll
      for (int j=0;j<4;j++) b[j]=Bs[kk][tx*4+j];
      #pragma unroll
      for (int i=0;i<4;i++){
        #pragma unroll
        for (int j=0;j<4;j++) acc[i][j] += a[i]*b[j];
      }
    }
  }
  #pragma unroll
  for (int i=0;i<4;i++){
    int row = row0 + ty*4 + i;
    int b = row >> 12, n = row & 4095;
    #pragma unroll
    for (int j=0;j<4;j++){
      int col = col0 + tx*4 + j;
      int which = col >> 9, rem = col & 511;
      int h = rem >> 6, d = rem & 63;
      size_t dst = ((size_t)(b*8+h)*N_ + n)*D_ + d;
      float val = acc[i][j];
      if (which == 0)      q[dst] = val * 0.125f;
      else if (which == 1) k[dst] = val;
      else                 v[dst] = val;
    }
  }
}

// ---------- 3. landmark means over groups of 16 tokens ----------
__global__ void lmk_k(const float* __restrict__ q, const float* __restrict__ k,
                      float* __restrict__ ql, float* __restrict__ kl){
  int idx = blockIdx.x*256 + threadIdx.x;        // (bh*256+i)*64+d
  int d = idx & 63, i = (idx >> 6) & 255, bh = idx >> 14;
  size_t base = ((size_t)bh*N_ + i*L_)*D_ + d;
  float sq=0.f, sk=0.f;
  #pragma unroll
  for (int tt=0;tt<L_;tt++){ sq += q[base + (size_t)tt*D_]; sk += k[base + (size_t)tt*D_]; }
  ql[idx] = sq*(1.f/L_); kl[idx] = sk*(1.f/L_);
}

// ---------- 4. attn2 = softmax(ql @ kl^T): block per (bh,i) ----------
__global__ __launch_bounds__(256) void attn2_k(const float* __restrict__ ql,
    const float* __restrict__ kl, float* __restrict__ a2){
  int i = blockIdx.x, bh = blockIdx.y, t = threadIdx.x;
  __shared__ float qrow[64];
  __shared__ float sm[4];
  if (t < 64) qrow[t] = ql[((size_t)bh*M_+i)*D_ + t];
  __syncthreads();
  const float* kr = kl + ((size_t)bh*M_+t)*D_;
  float s = 0.f;
  #pragma unroll
  for (int d=0;d<64;d++) s += qrow[d]*kr[d];
  float mx = blk_max256(s, sm);
  float e = expf(s - mx);
  float den = blk_sum256(e, sm);
  a2[((size_t)bh*M_+i)*M_ + t] = e/den;
}

// ---------- 5/6/7. pinv init: global scalar max of row/col abs sums ----------
__global__ void colrow_k(const float* __restrict__ a2, float* __restrict__ cs,
                         float* __restrict__ rs){
  int idx = blockIdx.x*256 + threadIdx.x;        // bh*256 + j
  int j = idx & 255, bh = idx >> 8;
  const float* base = a2 + (size_t)bh*M_*M_;
  float c=0.f, r=0.f;
  for (int i=0;i<M_;i++)  c += fabsf(base[(size_t)i*M_ + j]);
  for (int jj=0;jj<M_;jj++) r += fabsf(base[(size_t)j*M_ + jj]);
  cs[idx]=c; rs[idx]=r;
}
__global__ __launch_bounds__(256) void maxred_k(const float* __restrict__ cs,
    const float* __restrict__ rs, float* __restrict__ scal){
  __shared__ float sm[4];
  float cm=-1e30f, rm=-1e30f;
  for (int i=threadIdx.x;i<BH*M_;i+=256){ cm=fmaxf(cm,cs[i]); rm=fmaxf(rm,rs[i]); }
  cm = blk_max256(cm, sm);
  rm = blk_max256(rm, sm);
  if (threadIdx.x==0) scal[0] = 1.f/(cm*rm);
}
__global__ void initz_k(const float* __restrict__ a2, const float* __restrict__ scal,
                        float* __restrict__ z){
  int idx = blockIdx.x*256 + threadIdx.x;        // (bh*256+i)*256+j
  int j = idx & 255, i = (idx >> 8) & 255, bh = idx >> 16;
  z[idx] = a2[((size_t)bh*M_+j)*M_ + i] * scal[0];
}

// ---------- 8. Newton-Schulz batched GEMM: C = scale*(coef*A - A@B), 256^3 x32 ----------
__global__ __launch_bounds__(256) void ns_gemm_k(const float* __restrict__ A,
    const float* __restrict__ Bm, float* __restrict__ C, float scale, float coef){
  __shared__ float As[16][68];
  __shared__ float Bs[16][66];
  int batch = blockIdx.z;
  const float* Ab = A + (size_t)batch*M_*M_;
  const float* Bb = Bm + (size_t)batch*M_*M_;
  float* Cb = C + (size_t)batch*M_*M_;
  int t = threadIdx.x, tx = t & 15, ty = t >> 4;
  int row0 = blockIdx.y*64, col0 = blockIdx.x*64;
  float acc[4][4];
  #pragma unroll
  for (int i=0;i<4;i++){
    #pragma unroll
    for (int j=0;j<4;j++) acc[i][j]=0.f;
  }
  for (int k0=0;k0<M_;k0+=16){
    __syncthreads();
    #pragma unroll
    for (int it=0;it<4;it++){
      int flat = t + it*256;
      int ka = flat & 15, m = flat >> 4;
      As[ka][m] = Ab[(size_t)(row0+m)*M_ + (k0+ka)];
      int nn = flat & 63, kb = flat >> 6;
      Bs[kb][nn] = Bb[(size_t)(k0+kb)*M_ + (col0+nn)];
    }
    __syncthreads();
    #pragma unroll
    for (int kk=0;kk<16;kk++){
      float a[4], b[4];
      #pragma unroll
      for (int i=0;i<4;i++) a[i]=As[kk][ty*4+i];
      #pragma unroll
      for (int j=0;j<4;j++) b[j]=Bs[kk][tx*4+j];
      #pragma unroll
      for (int i=0;i<4;i++){
        #pragma unroll
        for (int j=0;j<4;j++) acc[i][j] += a[i]*b[j];
      }
    }
  }
  #pragma unroll
  for (int i=0;i<4;i++){
    int row = row0 + ty*4 + i;
    #pragma unroll
    for (int j=0;j<4;j++){
      int col = col0 + tx*4 + j;
      size_t o = (size_t)row*M_ + col;
      Cb[o] = scale*(coef*Ab[o] - acc[i][j]);
    }
  }
}

// ---------- 9. u = softmax(ql @ k^T) @ v, flash-style (online softmax over N) ----------
__global__ __launch_bounds__(256) void attn3v_k(const float* __restrict__ ql,
    const float* __restrict__ kk_, const float* __restrict__ vv, float* __restrict__ u){
  int bh = blockIdx.y, i0 = blockIdx.x*16, t = threadIdx.x;
  __shared__ float qs[16][64];
  __shared__ float kt[256][33];
  __shared__ float ps[16][264];
  __shared__ float m_s[16], l_s[16], al_s[16];
  for (int idx=t; idx<16*64; idx+=256){
    int r = idx >> 6, d = idx & 63;
    qs[r][d] = ql[((size_t)bh*M_ + i0 + r)*D_ + d];
  }
  if (t < 16){ m_s[t] = -1e30f; l_s[t] = 0.f; }
  int d = t & 63, g = t >> 6;
  float o0=0.f,o1=0.f,o2=0.f,o3=0.f;
  __syncthreads();
  for (int j0=0;j0<N_;j0+=256){
    float sc[16];
    #pragma unroll
    for (int r=0;r<16;r++) sc[r]=0.f;
    for (int dc=0;dc<64;dc+=32){
      __syncthreads();
      for (int it=0;it<32;it++){
        int flat = t + it*256;
        int j = flat >> 5, dd = flat & 31;
        kt[j][dd] = kk_[((size_t)bh*N_ + j0 + j)*D_ + dc + dd];
      }
      __syncthreads();
      #pragma unroll
      for (int dd=0;dd<32;dd++){
        float kv = kt[t][dd];
        #pragma unroll
        for (int r=0;r<16;r++) sc[r] += qs[r][dc+dd]*kv;
      }
    }
    #pragma unroll
    for (int r=0;r<16;r++) ps[r][t] = sc[r];
    __syncthreads();
    int r2 = t >> 4, l16 = t & 15;
    float lm = -1e30f;
    #pragma unroll
    for (int s=0;s<16;s++) lm = fmaxf(lm, ps[r2][l16 + s*16]);
    #pragma unroll
    for (int o=8;o;o>>=1) lm = fmaxf(lm, __shfl_down(lm,o,16));
    lm = __shfl(lm, 0, 16);
    float mold = m_s[r2];
    float mnew = fmaxf(mold, lm);
    float lsum = 0.f;
    #pragma unroll
    for (int s=0;s<16;s++){
      int j = l16 + s*16;
      float p = expf(ps[r2][j] - mnew);
      ps[r2][j] = p; lsum += p;
    }
    #pragma unroll
    for (int o=8;o;o>>=1) lsum += __shfl_down(lsum,o,16);
    if (l16 == 0){
      al_s[r2] = expf(mold - mnew);
      l_s[r2] = l_s[r2]*al_s[r2] + lsum;
      m_s[r2] = mnew;
    }
    __syncthreads();
    float a0 = al_s[g*4+0], a1 = al_s[g*4+1], a2 = al_s[g*4+2], a3 = al_s[g*4+3];
    o0 *= a0; o1 *= a1; o2 *= a2; o3 *= a3;
    const float* vb = vv + ((size_t)bh*N_ + j0)*D_ + d;
    for (int j=0;j<256;j++){
      float vx = vb[(size_t)j*D_];
      o0 += ps[g*4+0][j]*vx;
      o1 += ps[g*4+1][j]*vx;
      o2 += ps[g*4+2][j]*vx;
      o3 += ps[g*4+3][j]*vx;
    }
  }
  u[((size_t)bh*M_ + i0 + g*4+0)*D_ + d] = o0 / l_s[g*4+0];
  u[((size_t)bh*M_ + i0 + g*4+1)*D_ + d] = o1 / l_s[g*4+1];
  u[((size_t)bh*M_ + i0 + g*4+2)*D_ + d] = o2 / l_s[g*4+2];
  u[((size_t)bh*M_ + i0 + g*4+3)*D_ + d] = o3 / l_s[g*4+3];
}

// ---------- 10. w = z @ u : [256,256]@[256,64] per bh ----------
__global__ void zu_k(const float* __restrict__ z, const float* __restrict__ u,
                     float* __restrict__ w){
  int idx = blockIdx.x*256 + threadIdx.x;        // (bh*256+i)*64+d
  int d = idx & 63, i = (idx >> 6) & 255, bh = idx >> 14;
  const float* zr = z + ((size_t)bh*M_+i)*M_;
  const float* ub = u + (size_t)bh*M_*D_ + d;
  float acc = 0.f;
  for (int kk=0;kk<M_;kk++) acc += zr[kk]*ub[(size_t)kk*D_];
  w[idx] = acc;
}

// ---------- 11. out = softmax(q @ kl^T) @ w : exact softmax (m=256 keys) ----------
__global__ __launch_bounds__(256) void attn1w_k(const float* __restrict__ q,
    const float* __restrict__ kl, const float* __restrict__ w, float* __restrict__ out){
  int bh = blockIdx.y, n0 = blockIdx.x*16, t = threadIdx.x;
  __shared__ float qs[16][64];
  __shared__ float kt[256][33];
  __shared__ float ps[16][264];
  for (int idx=t; idx<16*64; idx+=256){
    int r = idx >> 6, d = idx & 63;
    qs[r][d] = q[((size_t)bh*N_ + n0 + r)*D_ + d];
  }
  float sc[16];
  #pragma unroll
  for (int r=0;r<16;r++) sc[r]=0.f;
  for (int dc=0;dc<64;dc+=32){
    __syncthreads();
    for (int it=0;it<32;it++){
      int flat = t + it*256;
      int j = flat >> 5, dd = flat & 31;
      kt[j][dd] = kl[((size_t)bh*M_ + j)*D_ + dc + dd];
    }
    __syncthreads();
    #pragma unroll
    for (int dd=0;dd<32;dd++){
      float kv = kt[t][dd];
      #pragma unroll
      for (int r=0;r<16;r++) sc[r] += qs[r][dc+dd]*kv;
    }
  }
  #pragma unroll
  for (int r=0;r<16;r++) ps[r][t] = sc[r];
  __syncthreads();
  int r2 = t >> 4, l16 = t & 15;
  float lm = -1e30f;
  #pragma unroll
  for (int s=0;s<16;s++) lm = fmaxf(lm, ps[r2][l16 + s*16]);
  #pragma unroll
  for (int o=8;o;o>>=1) lm = fmaxf(lm, __shfl_down(lm,o,16));
  lm = __shfl(lm, 0, 16);
  float lsum = 0.f;
  #pragma unroll
  for (int s=0;s<16;s++){
    int j = l16 + s*16;
    float p = expf(ps[r2][j] - lm);
    ps[r2][j] = p; lsum += p;
  }
  #pragma unroll
  for (int o=8;o;o>>=1) lsum += __shfl_down(lsum,o,16);
  lsum = __shfl(lsum, 0, 16);
  float inv = 1.f/lsum;
  #pragma unroll
  for (int s=0;s<16;s++) ps[r2][l16 + s*16] *= inv;
  __syncthreads();
  int d = t & 63, g = t >> 6;
  float c0=0.f,c1=0.f,c2=0.f,c3=0.f;
  const float* wb = w + (size_t)bh*M_*D_ + d;
  for (int j=0;j<256;j++){
    float wv = wb[(size_t)j*D_];
    c0 += ps[g*4+0][j]*wv;
    c1 += ps[g*4+1][j]*wv;
    c2 += ps[g*4+2][j]*wv;
    c3 += ps[g*4+3][j]*wv;
  }
  out[((size_t)bh*N_ + n0 + g*4+0)*D_ + d] = c0;
  out[((size_t)bh*N_ + n0 + g*4+1)*D_ + d] = c1;
  out[((size_t)bh*N_ + n0 + g*4+2)*D_ + d] = c2;
  out[((size_t)bh*N_ + n0 + g*4+3)*D_ + d] = c3;
}

// ---------- 12. depthwise conv residual over sequence dim ----------
__global__ void conv_k(const float* __restrict__ v, const float* __restrict__ cw,
                       float* __restrict__ out){
  int idx = blockIdx.x*256 + threadIdx.x;        // (bh*4096+n)*64+d
  int d = idx & 63, n = (idx >> 6) & 4095, bh = idx >> 18;
  int h = bh & 7;
  float acc = 0.f;
  #pragma unroll
  for (int kk=0;kk<33;kk++){
    int nn = n + kk - 16;
    if (nn >= 0 && nn < N_) acc += cw[h*33+kk]*v[((size_t)bh*N_+nn)*D_ + d];
  }
  out[idx] += acc;
}

// ---------- 13. final: y = x + gather(out) @ w_out + b_out ----------
__global__ __launch_bounds__(256) void final_k(const float* __restrict__ outb,
    const float* __restrict__ Wo, const float* __restrict__ bo,
    const float* __restrict__ x, float* __restrict__ y){
  __shared__ float As[16][68];
  __shared__ float Bs[16][66];
  int t = threadIdx.x, tx = t & 15, ty = t >> 4;
  int row0 = blockIdx.y*64, col0 = blockIdx.x*64;
  float acc[4][4];
  #pragma unroll
  for (int i=0;i<4;i++){
    #pragma unroll
    for (int j=0;j<4;j++) acc[i][j]=0.f;
  }
  for (int k0=0;k0<DIM_;k0+=16){
    __syncthreads();
    #pragma unroll
    for (int it=0;it<4;it++){
      int flat = t + it*256;
      int ka = flat & 15, m = flat >> 4;
      int row = row0+m, b = row >> 12, n = row & 4095;
      int kg = k0+ka, h = kg >> 6, dd = kg & 63;
      As[ka][m] = outb[((size_t)(b*8+h)*N_ + n)*D_ + dd];
      int nn = flat & 63, kb = flat >> 6;
      Bs[kb][nn] = Wo[(size_t)(k0+kb)*DIM_ + (col0+nn)];
    }
    __syncthreads();
    #pragma unroll
    for (int kk=0;kk<16;kk++){
      float a[4], b[4];
      #pragma unroll
      for (int i=0;i<4;i++) a[i]=As[kk][ty*4+i];
      #pragma unroll
      for (int j=0;j<4;j++) b[j]=Bs[kk][tx*4+j];
      #pragma unroll
      for (int i=0;i<4;i++){
        #pragma unroll
        for (int j=0;j<4;j++) acc[i][j] += a[i]*b[j];
      }
    }
  }
  #pragma unroll
  for (int i=0;i<4;i++){
    int row = row0 + ty*4 + i;
    #pragma unroll
    for (int j=0;j<4;j++){
      int col = col0 + tx*4 + j;
      size_t o = (size_t)row*DIM_ + col;
      y[o] = acc[i][j] + bo[col] + x[o];
    }
  }
}

extern "C" void kernel_launch(void* const* d_in, const int* in_sizes, int n_in,
                              void* d_out, int out_size, void* d_ws, size_t ws_size,
                              hipStream_t stream){
  (void)in_sizes; (void)n_in; (void)out_size; (void)ws_size;
  const float* x      = (const float*)d_in[0];
  const float* gamma  = (const float*)d_in[1];
  const float* beta   = (const float*)d_in[2];
  const float* w_qkv  = (const float*)d_in[3];
  const float* w_out  = (const float*)d_in[4];
  const float* b_out  = (const float*)d_in[5];
  const float* conv_w = (const float*)d_in[6];
  float* y = (float*)d_out;
  float* ws = (float*)d_ws;

  size_t off = 0;
  float* xn = ws + off;  off += (size_t)16384*DIM_;
  float* q  = ws + off;  off += (size_t)BH*N_*D_;
  float* k  = ws + off;  off += (size_t)BH*N_*D_;
  float* v  = ws + off;  off += (size_t)BH*N_*D_;
  float* ql = ws + off;  off += (size_t)BH*M_*D_;
  float* kl = ws + off;  off += (size_t)BH*M_*D_;
  float* a2 = ws + off;  off += (size_t)BH*M_*M_;
  float* z0 = ws + off;  off += (size_t)BH*M_*M_;
  float* z1 = ws + off;  off += (size_t)BH*M_*M_;
  float* az = ws + off;  off += (size_t)BH*M_*M_;
  float* t1 = ws + off;  off += (size_t)BH*M_*M_;
  float* t2 = ws + off;  off += (size_t)BH*M_*M_;
  float* u  = ws + off;  off += (size_t)BH*M_*D_;
  float* wz = ws + off;  off += (size_t)BH*M_*D_;
  float* ob = ws + off;  off += (size_t)BH*N_*D_;
  float* cs = ws + off;  off += (size_t)BH*M_;
  float* rs = ws + off;  off += (size_t)BH*M_;
  float* scal = ws + off; off += 2;

  ln_k<<<16384,256,0,stream>>>(x, gamma, beta, xn);
  gemm_qkv_k<<<dim3(24,256),256,0,stream>>>(xn, w_qkv, q, k, v);
  lmk_k<<<2048,256,0,stream>>>(q, k, ql, kl);
  attn2_k<<<dim3(256,32),256,0,stream>>>(ql, kl, a2);
  colrow_k<<<32,256,0,stream>>>(a2, cs, rs);
  maxred_k<<<1,256,0,stream>>>(cs, rs, scal);
  initz_k<<<8192,256,0,stream>>>(a2, scal, z0);

  float* zc = z0;
  float* zn = z1;
  for (int it=0; it<6; it++){
    ns_gemm_k<<<dim3(4,4,32),256,0,stream>>>(a2, zc, az, -1.f, 0.f);   // az = a2@z
    ns_gemm_k<<<dim3(4,4,32),256,0,stream>>>(az, az, t1, 1.f, 7.f);    // t1 = az@(7I-az)
    ns_gemm_k<<<dim3(4,4,32),256,0,stream>>>(az, t1, t2, 1.f, 15.f);   // t2 = az@(15I-t1)
    ns_gemm_k<<<dim3(4,4,32),256,0,stream>>>(zc, t2, zn, 0.25f, 13.f); // z' = 0.25 z@(13I-t2)
    float* tmp = zc; zc = zn; zn = tmp;
  }

  attn3v_k<<<dim3(16,32),256,0,stream>>>(ql, k, v, u);
  zu_k<<<2048,256,0,stream>>>(zc, u, wz);
  attn1w_k<<<dim3(256,32),256,0,stream>>>(q, kl, wz, ob);
  conv_k<<<32768,256,0,stream>>>(v, conv_w, ob);
  final_k<<<dim3(8,256),256,0,stream>>>(ob, w_out, b_out, x, y);
}

// Round 3
// 1146.081 us; speedup vs baseline: 2.3426x; 2.3426x over previous
//
#include <hip/hip_runtime.h>
#include <math.h>

#define BH 32
#define N_ 4096
#define D_ 64
#define M_ 256
#define L_ 16
#define DIM_ 512
#define K3_ 1536

typedef __attribute__((ext_vector_type(4))) float f32x4;
typedef __attribute__((ext_vector_type(8))) short s16x8;
typedef unsigned short ushort_t;

__device__ inline ushort_t f2bf(float f){
  union{float f; unsigned u;} v; v.f = f;
  unsigned r = v.u + 0x7fffu + ((v.u >> 16) & 1u);
  return (ushort_t)(r >> 16);
}
__device__ inline float bf2f(ushort_t b){
  union{unsigned u; float f;} v; v.u = ((unsigned)b) << 16; return v.f;
}

// ---------- reduction helpers ----------
__device__ inline float wave_sum(float v){
  #pragma unroll
  for (int o=32;o;o>>=1) v += __shfl_down(v,o,64);
  return v;
}
__device__ inline float wave_max(float v){
  #pragma unroll
  for (int o=32;o;o>>=1) v = fmaxf(v,__shfl_down(v,o,64));
  return v;
}
__device__ inline float blk_sum256(float v, float* sm){
  v = wave_sum(v);
  int lane = threadIdx.x & 63, wid = threadIdx.x >> 6;
  if (lane==0) sm[wid]=v;
  __syncthreads();
  float r = sm[0]+sm[1]+sm[2]+sm[3];
  __syncthreads();
  return r;
}
__device__ inline float blk_max256(float v, float* sm){
  v = wave_max(v);
  int lane = threadIdx.x & 63, wid = threadIdx.x >> 6;
  if (lane==0) sm[wid]=v;
  __syncthreads();
  float r = fmaxf(fmaxf(sm[0],sm[1]),fmaxf(sm[2],sm[3]));
  __syncthreads();
  return r;
}

// ---------- 1. LayerNorm -> bf16 ----------
__global__ __launch_bounds__(256) void ln_k(const float* __restrict__ x,
    const float* __restrict__ g, const float* __restrict__ bt, ushort_t* __restrict__ xn){
  int row = blockIdx.x, t = threadIdx.x;
  __shared__ float sm[4];
  const float* xr = x + (size_t)row*DIM_;
  float v0 = xr[t], v1 = xr[t+256];
  float mu = blk_sum256(v0+v1, sm) * (1.f/DIM_);
  float d0 = v0-mu, d1 = v1-mu;
  float var = blk_sum256(d0*d0+d1*d1, sm) * (1.f/DIM_);
  float rs = rsqrtf(var + 1e-5f);
  ushort_t* xo = xn + (size_t)row*DIM_;
  xo[t]     = f2bf(d0*rs*g[t]     + bt[t]);
  xo[t+256] = f2bf(d1*rs*g[t+256] + bt[t+256]);
}

// ---------- transpose fp32 [R][C] -> bf16 [C][R], batched via z ----------
__global__ __launch_bounds__(256) void twb_k(const float* __restrict__ src,
    ushort_t* __restrict__ dst, int R, int C){
  __shared__ ushort_t tile[64][66];
  size_t boff = (size_t)blockIdx.z * R * C;
  int r0 = blockIdx.y*64, c0 = blockIdx.x*64;
  int t = threadIdx.x, c = t & 63, r4 = t >> 6;
  #pragma unroll
  for (int i=0;i<16;i++){
    int rr = r4 + i*4;
    tile[c][rr] = f2bf(src[boff + (size_t)(r0+rr)*C + (c0+c)]);
  }
  __syncthreads();
  #pragma unroll
  for (int i=0;i<16;i++){
    int cc = r4 + i*4;
    dst[boff + (size_t)(c0+cc)*R + (r0 + c)] = tile[cc][c];
  }
}
// ---------- transpose bf16 [R][C] -> bf16 [C][R], batched ----------
__global__ __launch_bounds__(256) void tbb_k(const ushort_t* __restrict__ src,
    ushort_t* __restrict__ dst, int R, int C){
  __shared__ ushort_t tile[64][66];
  size_t boff = (size_t)blockIdx.z * R * C;
  int r0 = blockIdx.y*64, c0 = blockIdx.x*64;
  int t = threadIdx.x, c = t & 63, r4 = t >> 6;
  #pragma unroll
  for (int i=0;i<16;i++){
    int rr = r4 + i*4;
    tile[c][rr] = src[boff + (size_t)(r0+rr)*C + (c0+c)];
  }
  __syncthreads();
  #pragma unroll
  for (int i=0;i<16;i++){
    int cc = r4 + i*4;
    dst[boff + (size_t)(c0+cc)*R + (r0 + c)] = tile[cc][c];
  }
}

// ---------- 2. QKV GEMM bf16 MFMA: A[16384,512] @ Bt[1536,512]^T -> scatter q,k,v ----------
__global__ __launch_bounds__(256) void gemm_qkv_k(const ushort_t* __restrict__ A,
    const ushort_t* __restrict__ Bt, ushort_t* __restrict__ qb, ushort_t* __restrict__ kb,
    ushort_t* __restrict__ vb){
  __shared__ __align__(16) ushort_t As[128*72];
  __shared__ __align__(16) ushort_t Bs[128*72];
  int t = threadIdx.x;
  int lane = t & 63, wave = t >> 6;
  int l16 = lane & 15, quad = lane >> 4;
  int wm = (wave & 1) * 64, wn = (wave >> 1) * 64;
  int row0 = blockIdx.y * 128, col0 = blockIdx.x * 128;
  f32x4 acc[4][4];
  #pragma unroll
  for (int i=0;i<4;i++)
    #pragma unroll
    for (int j=0;j<4;j++) acc[i][j] = (f32x4){0.f,0.f,0.f,0.f};
  int sr = t >> 3, sc = (t & 7) * 8;
  for (int k0=0;k0<DIM_;k0+=64){
    __syncthreads();
    #pragma unroll
    for (int p=0;p<4;p++){
      int r = sr + p*32;
      *(uint4*)&As[r*72 + sc] = *(const uint4*)&A[(size_t)(row0+r)*DIM_ + k0 + sc];
      *(uint4*)&Bs[r*72 + sc] = *(const uint4*)&Bt[(size_t)(col0+r)*DIM_ + k0 + sc];
    }
    __syncthreads();
    s16x8 af[4][2], bf[4][2];
    #pragma unroll
    for (int mt=0;mt<4;mt++)
      #pragma unroll
      for (int kk=0;kk<2;kk++)
        af[mt][kk] = *(const s16x8*)&As[(wm + mt*16 + l16)*72 + kk*32 + quad*8];
    #pragma unroll
    for (int nt=0;nt<4;nt++)
      #pragma unroll
      for (int kk=0;kk<2;kk++)
        bf[nt][kk] = *(const s16x8*)&Bs[(wn + nt*16 + l16)*72 + kk*32 + quad*8];
    #pragma unroll
    for (int mt=0;mt<4;mt++)
      #pragma unroll
      for (int nt=0;nt<4;nt++)
        #pragma unroll
        for (int kk=0;kk<2;kk++)
          acc[mt][nt] = __builtin_amdgcn_mfma_f32_16x16x32_bf16(af[mt][kk], bf[nt][kk], acc[mt][nt], 0,0,0);
  }
  #pragma unroll
  for (int mt=0;mt<4;mt++){
    #pragma unroll
    for (int nt=0;nt<4;nt++){
      #pragma unroll
      for (int reg=0;reg<4;reg++){
        int row = row0 + wm + mt*16 + quad*4 + reg;
        int col = col0 + wn + nt*16 + l16;
        float val = acc[mt][nt][reg];
        int b = row >> 12, n = row & 4095;
        int which = col >> 9, rem = col & 511;
        int h = rem >> 6, d = rem & 63;
        size_t dst = ((size_t)((b<<3)+h)*N_ + n)*D_ + d;
        if (which==0)      qb[dst] = f2bf(val*0.125f);
        else if (which==1) kb[dst] = f2bf(val);
        else               vb[dst] = f2bf(val);
      }
    }
  }
}

// ---------- final GEMM bf16 MFMA: ob[16384,512] @ woutT[512,512]^T + b + x -> y fp32 ----------
__global__ __launch_bounds__(256) void final_k(const ushort_t* __restrict__ A,
    const ushort_t* __restrict__ Bt, const float* __restrict__ bo,
    const float* __restrict__ x, float* __restrict__ y){
  __shared__ __align__(16) ushort_t As[128*72];
  __shared__ __align__(16) ushort_t Bs[128*72];
  int t = threadIdx.x;
  int lane = t & 63, wave = t >> 6;
  int l16 = lane & 15, quad = lane >> 4;
  int wm = (wave & 1) * 64, wn = (wave >> 1) * 64;
  int row0 = blockIdx.y * 128, col0 = blockIdx.x * 128;
  f32x4 acc[4][4];
  #pragma unroll
  for (int i=0;i<4;i++)
    #pragma unroll
    for (int j=0;j<4;j++) acc[i][j] = (f32x4){0.f,0.f,0.f,0.f};
  int sr = t >> 3, sc = (t & 7) * 8;
  for (int k0=0;k0<DIM_;k0+=64){
    __syncthreads();
    #pragma unroll
    for (int p=0;p<4;p++){
      int r = sr + p*32;
      *(uint4*)&As[r*72 + sc] = *(const uint4*)&A[(size_t)(row0+r)*DIM_ + k0 + sc];
      *(uint4*)&Bs[r*72 + sc] = *(const uint4*)&Bt[(size_t)(col0+r)*DIM_ + k0 + sc];
    }
    __syncthreads();
    s16x8 af[4][2], bf[4][2];
    #pragma unroll
    for (int mt=0;mt<4;mt++)
      #pragma unroll
      for (int kk=0;kk<2;kk++)
        af[mt][kk] = *(const s16x8*)&As[(wm + mt*16 + l16)*72 + kk*32 + quad*8];
    #pragma unroll
    for (int nt=0;nt<4;nt++)
      #pragma unroll
      for (int kk=0;kk<2;kk++)
        bf[nt][kk] = *(const s16x8*)&Bs[(wn + nt*16 + l16)*72 + kk*32 + quad*8];
    #pragma unroll
    for (int mt=0;mt<4;mt++)
      #pragma unroll
      for (int nt=0;nt<4;nt++)
        #pragma unroll
        for (int kk=0;kk<2;kk++)
          acc[mt][nt] = __builtin_amdgcn_mfma_f32_16x16x32_bf16(af[mt][kk], bf[nt][kk], acc[mt][nt], 0,0,0);
  }
  #pragma unroll
  for (int mt=0;mt<4;mt++){
    #pragma unroll
    for (int nt=0;nt<4;nt++){
      #pragma unroll
      for (int reg=0;reg<4;reg++){
        int row = row0 + wm + mt*16 + quad*4 + reg;
        int col = col0 + wn + nt*16 + l16;
        size_t o = (size_t)row*DIM_ + col;
        y[o] = acc[mt][nt][reg] + bo[col] + x[o];
      }
    }
  }
}

// ---------- 3. landmark means ----------
__global__ void lmk_k(const ushort_t* __restrict__ q, const ushort_t* __restrict__ k,
                      float* __restrict__ ql, float* __restrict__ kl,
                      ushort_t* __restrict__ qlb, ushort_t* __restrict__ klb){
  int idx = blockIdx.x*256 + threadIdx.x;
  int d = idx & 63, i = (idx >> 6) & 255, bh = idx >> 14;
  size_t base = ((size_t)bh*N_ + i*L_)*D_ + d;
  float sq=0.f, sk=0.f;
  #pragma unroll
  for (int tt=0;tt<L_;tt++){ sq += bf2f(q[base + (size_t)tt*D_]); sk += bf2f(k[base + (size_t)tt*D_]); }
  sq *= (1.f/L_); sk *= (1.f/L_);
  ql[idx] = sq; kl[idx] = sk;
  qlb[idx] = f2bf(sq); klb[idx] = f2bf(sk);
}

// ---------- 4. attn2 = softmax(ql @ kl^T)  (fp32) ----------
__global__ __launch_bounds__(256) void attn2_k(const float* __restrict__ ql,
    const float* __restrict__ kl, float* __restrict__ a2){
  int i = blockIdx.x, bh = blockIdx.y, t = threadIdx.x;
  __shared__ float qrow[64];
  __shared__ float sm[4];
  if (t < 64) qrow[t] = ql[((size_t)bh*M_+i)*D_ + t];
  __syncthreads();
  const float* kr = kl + ((size_t)bh*M_+t)*D_;
  float s = 0.f;
  #pragma unroll
  for (int d=0;d<64;d++) s += qrow[d]*kr[d];
  float mx = blk_max256(s, sm);
  float e = expf(s - mx);
  float den = blk_sum256(e, sm);
  a2[((size_t)bh*M_+i)*M_ + t] = e/den;
}

// ---------- pinv init ----------
__global__ void colrow_k(const float* __restrict__ a2, float* __restrict__ cs,
                         float* __restrict__ rs){
  int idx = blockIdx.x*256 + threadIdx.x;
  int j = idx & 255, bh = idx >> 8;
  const float* base = a2 + (size_t)bh*M_*M_;
  float c=0.f, r=0.f;
  for (int i=0;i<M_;i++)  c += fabsf(base[(size_t)i*M_ + j]);
  for (int jj=0;jj<M_;jj++) r += fabsf(base[(size_t)j*M_ + jj]);
  cs[idx]=c; rs[idx]=r;
}
__global__ __launch_bounds__(256) void maxred_k(const float* __restrict__ cs,
    const float* __restrict__ rs, float* __restrict__ scal){
  __shared__ float sm[4];
  float cm=-1e30f, rm=-1e30f;
  for (int i=threadIdx.x;i<BH*M_;i+=256){ cm=fmaxf(cm,cs[i]); rm=fmaxf(rm,rs[i]); }
  cm = blk_max256(cm, sm);
  rm = blk_max256(rm, sm);
  if (threadIdx.x==0) scal[0] = 1.f/(cm*rm);
}
__global__ void initz_k(const float* __restrict__ a2, const float* __restrict__ scal,
                        float* __restrict__ z){
  int idx = blockIdx.x*256 + threadIdx.x;
  int j = idx & 255, i = (idx >> 8) & 255, bh = idx >> 16;
  z[idx] = a2[((size_t)bh*M_+j)*M_ + i] * scal[0];
}

// ---------- Newton-Schulz fp32 GEMM: C = scale*(coef*A - A@B) ----------
__global__ __launch_bounds__(256) void ns_gemm_k(const float* __restrict__ A,
    const float* __restrict__ Bm, float* __restrict__ C, float scale, float coef){
  __shared__ __align__(16) float As[16][68];
  __shared__ __align__(16) float Bs[16][68];
  int batch = blockIdx.z;
  const float* Ab = A + (size_t)batch*M_*M_;
  const float* Bb = Bm + (size_t)batch*M_*M_;
  float* Cb = C + (size_t)batch*M_*M_;
  int t = threadIdx.x, tx = t & 15, ty = t >> 4;
  int row0 = blockIdx.y*64, col0 = blockIdx.x*64;
  float acc[4][4];
  #pragma unroll
  for (int i=0;i<4;i++)
    #pragma unroll
    for (int j=0;j<4;j++) acc[i][j]=0.f;
  for (int k0=0;k0<M_;k0+=16){
    __syncthreads();
    #pragma unroll
    for (int it=0;it<4;it++){
      int flat = t + it*256;
      int ka = flat & 15, m = flat >> 4;
      As[ka][m] = Ab[(size_t)(row0+m)*M_ + (k0+ka)];
      int nn = flat & 63, kb = flat >> 6;
      Bs[kb][nn] = Bb[(size_t)(k0+kb)*M_ + (col0+nn)];
    }
    __syncthreads();
    #pragma unroll
    for (int kk=0;kk<16;kk++){
      float4 a4 = *(const float4*)&As[kk][ty*4];
      float4 b4 = *(const float4*)&Bs[kk][tx*4];
      float a[4] = {a4.x,a4.y,a4.z,a4.w};
      float b[4] = {b4.x,b4.y,b4.z,b4.w};
      #pragma unroll
      for (int i=0;i<4;i++)
        #pragma unroll
        for (int j=0;j<4;j++) acc[i][j] += a[i]*b[j];
    }
  }
  #pragma unroll
  for (int i=0;i<4;i++){
    int row = row0 + ty*4 + i;
    #pragma unroll
    for (int j=0;j<4;j++){
      int col = col0 + tx*4 + j;
      size_t o = (size_t)row*M_ + col;
      Cb[o] = scale*(coef*Ab[o] - acc[i][j]);
    }
  }
}

// ---------- fused MFMA attention (flash-style), 16 q-rows per block ----------
template<int NKEYS, bool SCATTER>
__global__ __launch_bounds__(256) void attn_k(const ushort_t* __restrict__ Q,
    const ushort_t* __restrict__ Kb, const ushort_t* __restrict__ VT,
    float* __restrict__ uout, ushort_t* __restrict__ ob, int nqrows){
  __shared__ __align__(16) ushort_t Qs[16*72];
  __shared__ __align__(16) ushort_t Ks[128*72];
  __shared__ __align__(16) ushort_t Vs[64*136];
  __shared__ __align__(16) ushort_t Pb[16*136];
  __shared__ float ps[16*132];
  __shared__ float m_s[16], l_s[16], al_s[16];
  int bh = blockIdx.y, i0 = blockIdx.x*16;
  int t = threadIdx.x, wave = t >> 6, lane = t & 63;
  int l16 = lane & 15, quad = lane >> 4;
  if (t < 128)
    *(uint4*)&Qs[(t>>3)*72 + (t&7)*8] =
      *(const uint4*)&Q[((size_t)bh*nqrows + i0 + (t>>3))*D_ + (t&7)*8];
  if (t < 16){ m_s[t] = -1e30f; l_s[t] = 0.f; }
  f32x4 oacc = (f32x4){0.f,0.f,0.f,0.f};
  __syncthreads();
  for (int j0=0;j0<NKEYS;j0+=128){
    __syncthreads();
    #pragma unroll
    for (int p=0;p<4;p++){
      int key = (t>>3) + p*32;
      *(uint4*)&Ks[key*72 + (t&7)*8] =
        *(const uint4*)&Kb[((size_t)bh*NKEYS + j0 + key)*D_ + (t&7)*8];
    }
    #pragma unroll
    for (int p=0;p<4;p++){
      int d = t>>2, k8 = (t&3)*8 + p*32;
      *(uint4*)&Vs[d*136 + k8] =
        *(const uint4*)&VT[((size_t)bh*D_ + d)*NKEYS + j0 + k8];
    }
    __syncthreads();
    s16x8 a0 = *(const s16x8*)&Qs[l16*72 + quad*8];
    s16x8 a1 = *(const s16x8*)&Qs[l16*72 + 32 + quad*8];
    #pragma unroll
    for (int nt=0;nt<2;nt++){
      int ktile = wave*2 + nt;
      s16x8 b0 = *(const s16x8*)&Ks[(ktile*16 + l16)*72 + quad*8];
      s16x8 b1 = *(const s16x8*)&Ks[(ktile*16 + l16)*72 + 32 + quad*8];
      f32x4 s = (f32x4){0.f,0.f,0.f,0.f};
      s = __builtin_amdgcn_mfma_f32_16x16x32_bf16(a0, b0, s, 0,0,0);
      s = __builtin_amdgcn_mfma_f32_16x16x32_bf16(a1, b1, s, 0,0,0);
      #pragma unroll
      for (int reg=0;reg<4;reg++)
        ps[(quad*4+reg)*132 + ktile*16 + l16] = s[reg];
    }
    __syncthreads();
    {
      int r2 = t >> 4, c = t & 15;
      float lm = -1e30f;
      #pragma unroll
      for (int s=0;s<8;s++) lm = fmaxf(lm, ps[r2*132 + c + s*16]);
      #pragma unroll
      for (int o=8;o;o>>=1) lm = fmaxf(lm, __shfl_down(lm,o,16));
      lm = __shfl(lm, 0, 16);
      float mold = m_s[r2];
      float mnew = fmaxf(mold, lm);
      float lsum = 0.f;
      #pragma unroll
      for (int s=0;s<8;s++){
        float p = expf(ps[r2*132 + c + s*16] - mnew);
        Pb[r2*136 + c + s*16] = f2bf(p);
        lsum += p;
      }
      #pragma unroll
      for (int o=8;o;o>>=1) lsum += __shfl_down(lsum,o,16);
      if (c==0){
        float al = expf(mold - mnew);
        al_s[r2] = al;
        l_s[r2] = l_s[r2]*al + lsum;
        m_s[r2] = mnew;
      }
    }
    __syncthreads();
    #pragma unroll
    for (int reg=0;reg<4;reg++) oacc[reg] *= al_s[quad*4+reg];
    #pragma unroll
    for (int ks=0;ks<4;ks++){
      s16x8 a = *(const s16x8*)&Pb[l16*136 + ks*32 + quad*8];
      s16x8 b = *(const s16x8*)&Vs[(wave*16 + l16)*136 + ks*32 + quad*8];
      oacc = __builtin_amdgcn_mfma_f32_16x16x32_bf16(a, b, oacc, 0,0,0);
    }
  }
  #pragma unroll
  for (int reg=0;reg<4;reg++){
    int row = quad*4 + reg;
    float val = oacc[reg] / l_s[row];
    if (!SCATTER){
      uout[((size_t)bh*nqrows + i0 + row)*D_ + wave*16 + l16] = val;
    } else {
      int n = i0 + row, b = bh >> 3, h = bh & 7;
      ob[((size_t)(b*N_ + n))*DIM_ + h*D_ + wave*16 + l16] = f2bf(val);
    }
  }
}

// ---------- w = z @ u (fp32) ----------
__global__ void zu_k(const float* __restrict__ z, const float* __restrict__ u,
                     float* __restrict__ w){
  int idx = blockIdx.x*256 + threadIdx.x;
  int d = idx & 63, i = (idx >> 6) & 255, bh = idx >> 14;
  const float* zr = z + ((size_t)bh*M_+i)*M_;
  const float* ub = u + (size_t)bh*M_*D_ + d;
  float acc = 0.f;
  for (int kk=0;kk<M_;kk++) acc += zr[kk]*ub[(size_t)kk*D_];
  w[idx] = acc;
}

// ---------- depthwise conv residual: ob += conv(v) (bf16 RMW) ----------
__global__ void conv_k(const ushort_t* __restrict__ v, const float* __restrict__ cw,
                       ushort_t* __restrict__ ob){
  int idx = blockIdx.x*256 + threadIdx.x;
  int d = idx & 63, n = (idx >> 6) & 4095, bh = idx >> 18;
  int h = bh & 7, b = bh >> 3;
  float acc = 0.f;
  #pragma unroll
  for (int kk=0;kk<33;kk++){
    int nn = n + kk - 16;
    if (nn >= 0 && nn < N_) acc += cw[h*33+kk]*bf2f(v[((size_t)bh*N_+nn)*D_ + d]);
  }
  size_t oi = ((size_t)(b*N_ + n))*DIM_ + h*D_ + d;
  ob[oi] = f2bf(bf2f(ob[oi]) + acc);
}

extern "C" void kernel_launch(void* const* d_in, const int* in_sizes, int n_in,
                              void* d_out, int out_size, void* d_ws, size_t ws_size,
                              hipStream_t stream){
  (void)in_sizes; (void)n_in; (void)out_size; (void)ws_size;
  const float* x      = (const float*)d_in[0];
  const float* gamma  = (const float*)d_in[1];
  const float* beta   = (const float*)d_in[2];
  const float* w_qkv  = (const float*)d_in[3];
  const float* w_out  = (const float*)d_in[4];
  const float* b_out  = (const float*)d_in[5];
  const float* conv_w = (const float*)d_in[6];
  float* y = (float*)d_out;
  float* ws = (float*)d_ws;

  size_t off = 0;
  ushort_t* xnb   = (ushort_t*)(ws + off); off += 4194304;
  ushort_t* qb    = (ushort_t*)(ws + off); off += 4194304;
  ushort_t* kb    = (ushort_t*)(ws + off); off += 4194304;
  ushort_t* vb    = (ushort_t*)(ws + off); off += 4194304;
  ushort_t* vT    = (ushort_t*)(ws + off); off += 4194304;
  ushort_t* wqkvT = (ushort_t*)(ws + off); off += 393216;
  ushort_t* woutT = (ushort_t*)(ws + off); off += 131072;
  ushort_t* qlb   = (ushort_t*)(ws + off); off += 262144;
  ushort_t* klb   = (ushort_t*)(ws + off); off += 262144;
  ushort_t* wzT   = (ushort_t*)(ws + off); off += 262144;
  ushort_t* ob    = (ushort_t*)(ws + off); off += 4194304;
  float* ql = ws + off;  off += 524288;
  float* kl = ws + off;  off += 524288;
  float* a2 = ws + off;  off += 2097152;
  float* z0 = ws + off;  off += 2097152;
  float* z1 = ws + off;  off += 2097152;
  float* az = ws + off;  off += 2097152;
  float* t1 = ws + off;  off += 2097152;
  float* t2 = ws + off;  off += 2097152;
  float* u  = ws + off;  off += 524288;
  float* wz = ws + off;  off += 524288;
  float* cs = ws + off;  off += 8192;
  float* rs = ws + off;  off += 8192;
  float* scal = ws + off; off += 2;

  ln_k<<<16384,256,0,stream>>>(x, gamma, beta, xnb);
  twb_k<<<dim3(24,8,1),256,0,stream>>>(w_qkv, wqkvT, 512, 1536);
  twb_k<<<dim3(8,8,1),256,0,stream>>>(w_out, woutT, 512, 512);
  gemm_qkv_k<<<dim3(12,128),256,0,stream>>>(xnb, wqkvT, qb, kb, vb);
  tbb_k<<<dim3(1,64,32),256,0,stream>>>(vb, vT, 4096, 64);
  lmk_k<<<2048,256,0,stream>>>(qb, kb, ql, kl, qlb, klb);
  attn2_k<<<dim3(256,32),256,0,stream>>>(ql, kl, a2);
  colrow_k<<<32,256,0,stream>>>(a2, cs, rs);
  maxred_k<<<1,256,0,stream>>>(cs, rs, scal);
  initz_k<<<8192,256,0,stream>>>(a2, scal, z0);

  float* zc = z0;
  float* zn = z1;
  for (int it=0; it<6; it++){
    ns_gemm_k<<<dim3(4,4,32),256,0,stream>>>(a2, zc, az, -1.f, 0.f);
    ns_gemm_k<<<dim3(4,4,32),256,0,stream>>>(az, az, t1, 1.f, 7.f);
    ns_gemm_k<<<dim3(4,4,32),256,0,stream>>>(az, t1, t2, 1.f, 15.f);
    ns_gemm_k<<<dim3(4,4,32),256,0,stream>>>(zc, t2, zn, 0.25f, 13.f);
    float* tmp = zc; zc = zn; zn = tmp;
  }

  attn_k<4096,false><<<dim3(16,32),256,0,stream>>>(qlb, kb, vT, u, (ushort_t*)nullptr, 256);
  zu_k<<<2048,256,0,stream>>>(zc, u, wz);
  twb_k<<<dim3(1,4,32),256,0,stream>>>(wz, wzT, 256, 64);
  attn_k<256,true><<<dim3(256,32),256,0,stream>>>(qb, klb, wzT, (float*)nullptr, ob, 4096);
  conv_k<<<32768,256,0,stream>>>(vb, conv_w, ob);
  final_k<<<dim3(4,128),256,0,stream>>>(ob, woutT, b_out, x, y);
}

// Round 4
// 956.097 us; speedup vs baseline: 2.8081x; 1.1987x over previous
//
#include <hip/hip_runtime.h>
#include <math.h>

#define BH 32
#define N_ 4096
#define D_ 64
#define M_ 256
#define L_ 16
#define DIM_ 512
#define K3_ 1536

typedef __attribute__((ext_vector_type(4))) float f32x4;
typedef __attribute__((ext_vector_type(8))) short s16x8;
typedef unsigned short ushort_t;

__device__ inline ushort_t f2bf(float f){
  union{float f; unsigned u;} v; v.f = f;
  unsigned r = v.u + 0x7fffu + ((v.u >> 16) & 1u);
  return (ushort_t)(r >> 16);
}
__device__ inline float bf2f(ushort_t b){
  union{unsigned u; float f;} v; v.u = ((unsigned)b) << 16; return v.f;
}

// ---------- reduction helpers ----------
__device__ inline float wave_sum(float v){
  #pragma unroll
  for (int o=32;o;o>>=1) v += __shfl_down(v,o,64);
  return v;
}
__device__ inline float wave_max(float v){
  #pragma unroll
  for (int o=32;o;o>>=1) v = fmaxf(v,__shfl_down(v,o,64));
  return v;
}
__device__ inline float blk_sum256(float v, float* sm){
  v = wave_sum(v);
  int lane = threadIdx.x & 63, wid = threadIdx.x >> 6;
  if (lane==0) sm[wid]=v;
  __syncthreads();
  float r = sm[0]+sm[1]+sm[2]+sm[3];
  __syncthreads();
  return r;
}
__device__ inline float blk_max256(float v, float* sm){
  v = wave_max(v);
  int lane = threadIdx.x & 63, wid = threadIdx.x >> 6;
  if (lane==0) sm[wid]=v;
  __syncthreads();
  float r = fmaxf(fmaxf(sm[0],sm[1]),fmaxf(sm[2],sm[3]));
  __syncthreads();
  return r;
}

// ---------- 1. LayerNorm -> bf16 ----------
__global__ __launch_bounds__(256) void ln_k(const float* __restrict__ x,
    const float* __restrict__ g, const float* __restrict__ bt, ushort_t* __restrict__ xn){
  int row = blockIdx.x, t = threadIdx.x;
  __shared__ float sm[4];
  const float* xr = x + (size_t)row*DIM_;
  float v0 = xr[t], v1 = xr[t+256];
  float mu = blk_sum256(v0+v1, sm) * (1.f/DIM_);
  float d0 = v0-mu, d1 = v1-mu;
  float var = blk_sum256(d0*d0+d1*d1, sm) * (1.f/DIM_);
  float rs = rsqrtf(var + 1e-5f);
  ushort_t* xo = xn + (size_t)row*DIM_;
  xo[t]     = f2bf(d0*rs*g[t]     + bt[t]);
  xo[t+256] = f2bf(d1*rs*g[t+256] + bt[t+256]);
}

// ---------- transpose fp32 [R][C] -> bf16 [C][R], batched via z ----------
__global__ __launch_bounds__(256) void twb_k(const float* __restrict__ src,
    ushort_t* __restrict__ dst, int R, int C){
  __shared__ ushort_t tile[64][66];
  size_t boff = (size_t)blockIdx.z * R * C;
  int r0 = blockIdx.y*64, c0 = blockIdx.x*64;
  int t = threadIdx.x, c = t & 63, r4 = t >> 6;
  #pragma unroll
  for (int i=0;i<16;i++){
    int rr = r4 + i*4;
    tile[c][rr] = f2bf(src[boff + (size_t)(r0+rr)*C + (c0+c)]);
  }
  __syncthreads();
  #pragma unroll
  for (int i=0;i<16;i++){
    int cc = r4 + i*4;
    dst[boff + (size_t)(c0+cc)*R + (r0 + c)] = tile[cc][c];
  }
}
// ---------- transpose bf16 [R][C] -> bf16 [C][R], batched ----------
__global__ __launch_bounds__(256) void tbb_k(const ushort_t* __restrict__ src,
    ushort_t* __restrict__ dst, int R, int C){
  __shared__ ushort_t tile[64][66];
  size_t boff = (size_t)blockIdx.z * R * C;
  int r0 = blockIdx.y*64, c0 = blockIdx.x*64;
  int t = threadIdx.x, c = t & 63, r4 = t >> 6;
  #pragma unroll
  for (int i=0;i<16;i++){
    int rr = r4 + i*4;
    tile[c][rr] = src[boff + (size_t)(r0+rr)*C + (c0+c)];
  }
  __syncthreads();
  #pragma unroll
  for (int i=0;i<16;i++){
    int cc = r4 + i*4;
    dst[boff + (size_t)(c0+cc)*R + (r0 + c)] = tile[cc][c];
  }
}

// ---------- 2. QKV GEMM bf16 MFMA ----------
__global__ __launch_bounds__(256) void gemm_qkv_k(const ushort_t* __restrict__ A,
    const ushort_t* __restrict__ Bt, ushort_t* __restrict__ qb, ushort_t* __restrict__ kb,
    ushort_t* __restrict__ vb){
  __shared__ __align__(16) ushort_t As[128*72];
  __shared__ __align__(16) ushort_t Bs[128*72];
  int t = threadIdx.x;
  int lane = t & 63, wave = t >> 6;
  int l16 = lane & 15, quad = lane >> 4;
  int wm = (wave & 1) * 64, wn = (wave >> 1) * 64;
  int row0 = blockIdx.y * 128, col0 = blockIdx.x * 128;
  f32x4 acc[4][4];
  #pragma unroll
  for (int i=0;i<4;i++)
    #pragma unroll
    for (int j=0;j<4;j++) acc[i][j] = (f32x4){0.f,0.f,0.f,0.f};
  int sr = t >> 3, sc = (t & 7) * 8;
  for (int k0=0;k0<DIM_;k0+=64){
    __syncthreads();
    #pragma unroll
    for (int p=0;p<4;p++){
      int r = sr + p*32;
      *(uint4*)&As[r*72 + sc] = *(const uint4*)&A[(size_t)(row0+r)*DIM_ + k0 + sc];
      *(uint4*)&Bs[r*72 + sc] = *(const uint4*)&Bt[(size_t)(col0+r)*DIM_ + k0 + sc];
    }
    __syncthreads();
    s16x8 af[4][2], bf[4][2];
    #pragma unroll
    for (int mt=0;mt<4;mt++)
      #pragma unroll
      for (int kk=0;kk<2;kk++)
        af[mt][kk] = *(const s16x8*)&As[(wm + mt*16 + l16)*72 + kk*32 + quad*8];
    #pragma unroll
    for (int nt=0;nt<4;nt++)
      #pragma unroll
      for (int kk=0;kk<2;kk++)
        bf[nt][kk] = *(const s16x8*)&Bs[(wn + nt*16 + l16)*72 + kk*32 + quad*8];
    #pragma unroll
    for (int mt=0;mt<4;mt++)
      #pragma unroll
      for (int nt=0;nt<4;nt++)
        #pragma unroll
        for (int kk=0;kk<2;kk++)
          acc[mt][nt] = __builtin_amdgcn_mfma_f32_16x16x32_bf16(af[mt][kk], bf[nt][kk], acc[mt][nt], 0,0,0);
  }
  #pragma unroll
  for (int mt=0;mt<4;mt++){
    #pragma unroll
    for (int nt=0;nt<4;nt++){
      #pragma unroll
      for (int reg=0;reg<4;reg++){
        int row = row0 + wm + mt*16 + quad*4 + reg;
        int col = col0 + wn + nt*16 + l16;
        float val = acc[mt][nt][reg];
        int b = row >> 12, n = row & 4095;
        int which = col >> 9, rem = col & 511;
        int h = rem >> 6, d = rem & 63;
        size_t dst = ((size_t)((b<<3)+h)*N_ + n)*D_ + d;
        if (which==0)      qb[dst] = f2bf(val*0.125f);
        else if (which==1) kb[dst] = f2bf(val);
        else               vb[dst] = f2bf(val);
      }
    }
  }
}

// ---------- final GEMM bf16 MFMA ----------
__global__ __launch_bounds__(256) void final_k(const ushort_t* __restrict__ A,
    const ushort_t* __restrict__ Bt, const float* __restrict__ bo,
    const float* __restrict__ x, float* __restrict__ y){
  __shared__ __align__(16) ushort_t As[128*72];
  __shared__ __align__(16) ushort_t Bs[128*72];
  int t = threadIdx.x;
  int lane = t & 63, wave = t >> 6;
  int l16 = lane & 15, quad = lane >> 4;
  int wm = (wave & 1) * 64, wn = (wave >> 1) * 64;
  int row0 = blockIdx.y * 128, col0 = blockIdx.x * 128;
  f32x4 acc[4][4];
  #pragma unroll
  for (int i=0;i<4;i++)
    #pragma unroll
    for (int j=0;j<4;j++) acc[i][j] = (f32x4){0.f,0.f,0.f,0.f};
  int sr = t >> 3, sc = (t & 7) * 8;
  for (int k0=0;k0<DIM_;k0+=64){
    __syncthreads();
    #pragma unroll
    for (int p=0;p<4;p++){
      int r = sr + p*32;
      *(uint4*)&As[r*72 + sc] = *(const uint4*)&A[(size_t)(row0+r)*DIM_ + k0 + sc];
      *(uint4*)&Bs[r*72 + sc] = *(const uint4*)&Bt[(size_t)(col0+r)*DIM_ + k0 + sc];
    }
    __syncthreads();
    s16x8 af[4][2], bf[4][2];
    #pragma unroll
    for (int mt=0;mt<4;mt++)
      #pragma unroll
      for (int kk=0;kk<2;kk++)
        af[mt][kk] = *(const s16x8*)&As[(wm + mt*16 + l16)*72 + kk*32 + quad*8];
    #pragma unroll
    for (int nt=0;nt<4;nt++)
      #pragma unroll
      for (int kk=0;kk<2;kk++)
        bf[nt][kk] = *(const s16x8*)&Bs[(wn + nt*16 + l16)*72 + kk*32 + quad*8];
    #pragma unroll
    for (int mt=0;mt<4;mt++)
      #pragma unroll
      for (int nt=0;nt<4;nt++)
        #pragma unroll
        for (int kk=0;kk<2;kk++)
          acc[mt][nt] = __builtin_amdgcn_mfma_f32_16x16x32_bf16(af[mt][kk], bf[nt][kk], acc[mt][nt], 0,0,0);
  }
  #pragma unroll
  for (int mt=0;mt<4;mt++){
    #pragma unroll
    for (int nt=0;nt<4;nt++){
      #pragma unroll
      for (int reg=0;reg<4;reg++){
        int row = row0 + wm + mt*16 + quad*4 + reg;
        int col = col0 + wn + nt*16 + l16;
        size_t o = (size_t)row*DIM_ + col;
        y[o] = acc[mt][nt][reg] + bo[col] + x[o];
      }
    }
  }
}

// ---------- 3. landmark means ----------
__global__ void lmk_k(const ushort_t* __restrict__ q, const ushort_t* __restrict__ k,
                      float* __restrict__ ql, float* __restrict__ kl,
                      ushort_t* __restrict__ qlb, ushort_t* __restrict__ klb){
  int idx = blockIdx.x*256 + threadIdx.x;
  int d = idx & 63, i = (idx >> 6) & 255, bh = idx >> 14;
  size_t base = ((size_t)bh*N_ + i*L_)*D_ + d;
  float sq=0.f, sk=0.f;
  #pragma unroll
  for (int tt=0;tt<L_;tt++){ sq += bf2f(q[base + (size_t)tt*D_]); sk += bf2f(k[base + (size_t)tt*D_]); }
  sq *= (1.f/L_); sk *= (1.f/L_);
  ql[idx] = sq; kl[idx] = sk;
  qlb[idx] = f2bf(sq); klb[idx] = f2bf(sk);
}

// ---------- 4. attn2 = softmax(ql @ kl^T)  -> fp32 + bf16 splits ----------
__global__ __launch_bounds__(256) void attn2_k(const float* __restrict__ ql,
    const float* __restrict__ kl, float* __restrict__ a2,
    ushort_t* __restrict__ a2h, ushort_t* __restrict__ a2l){
  int i = blockIdx.x, bh = blockIdx.y, t = threadIdx.x;
  __shared__ float qrow[64];
  __shared__ float sm[4];
  if (t < 64) qrow[t] = ql[((size_t)bh*M_+i)*D_ + t];
  __syncthreads();
  const float* kr = kl + ((size_t)bh*M_+t)*D_;
  float s = 0.f;
  #pragma unroll
  for (int d=0;d<64;d++) s += qrow[d]*kr[d];
  float mx = blk_max256(s, sm);
  float e = expf(s - mx);
  float den = blk_sum256(e, sm);
  float p = e/den;
  size_t idx = ((size_t)bh*M_+i)*M_ + t;
  a2[idx] = p;
  ushort_t hh = f2bf(p);
  a2h[idx] = hh;
  a2l[idx] = f2bf(p - bf2f(hh));
}

// ---------- pinv init ----------
__global__ void colrow_k(const float* __restrict__ a2, float* __restrict__ cs,
                         float* __restrict__ rs){
  int idx = blockIdx.x*256 + threadIdx.x;
  int j = idx & 255, bh = idx >> 8;
  const float* base = a2 + (size_t)bh*M_*M_;
  float c=0.f;
  for (int i=0;i<M_;i++)  c += fabsf(base[(size_t)i*M_ + j]);
  float r=0.f;
  const float4* rowp = (const float4*)(base + (size_t)j*M_);
  for (int q=0;q<M_/4;q++){
    float4 v = rowp[q];
    r += fabsf(v.x)+fabsf(v.y)+fabsf(v.z)+fabsf(v.w);
  }
  cs[idx]=c; rs[idx]=r;
}
__global__ __launch_bounds__(256) void maxred_k(const float* __restrict__ cs,
    const float* __restrict__ rs, float* __restrict__ scal){
  __shared__ float sm[4];
  float cm=-1e30f, rm=-1e30f;
  for (int i=threadIdx.x;i<BH*M_;i+=256){ cm=fmaxf(cm,cs[i]); rm=fmaxf(rm,rs[i]); }
  cm = blk_max256(cm, sm);
  rm = blk_max256(rm, sm);
  if (threadIdx.x==0) scal[0] = 1.f/(cm*rm);
}

// ---------- initz: z0 = scal * a2^T  -> f32 + splits (normal) + splits (transposed) ----------
// zT = scal*a2 (same orientation as a2); z = (scal*a2)^T via LDS tile transpose.
__global__ __launch_bounds__(256) void initz2_k(const float* __restrict__ a2,
    const float* __restrict__ scal, float* __restrict__ zf,
    ushort_t* __restrict__ zh, ushort_t* __restrict__ zl,
    ushort_t* __restrict__ zTh, ushort_t* __restrict__ zTl){
  __shared__ float tile[64][65];
  int bh = blockIdx.z;
  size_t mo = (size_t)bh*M_*M_;
  float s = scal[0];
  int r0 = blockIdx.y*64, c0 = blockIdx.x*64;
  int t = threadIdx.x, c = t & 63, r4 = t >> 6;
  #pragma unroll
  for (int i=0;i<16;i++){
    int rr = r4 + i*4;
    float v = a2[mo + (size_t)(r0+rr)*M_ + c0 + c] * s;
    tile[rr][c] = v;
    ushort_t hh = f2bf(v);
    size_t oi = mo + (size_t)(r0+rr)*M_ + c0 + c;
    zTh[oi] = hh;
    zTl[oi] = f2bf(v - bf2f(hh));
  }
  __syncthreads();
  #pragma unroll
  for (int i=0;i<16;i++){
    int zr = r4 + i*4;                       // row of z within [c0, c0+64)
    float v = tile[c][zr];                   // = s*a2[r0+c][c0+zr] = z[c0+zr][r0+c]
    size_t oi = mo + (size_t)(c0+zr)*M_ + r0 + c;
    zf[oi] = v;
    ushort_t hh = f2bf(v);
    zh[oi] = hh;
    zl[oi] = f2bf(v - bf2f(hh));
  }
}

// ---------- Newton-Schulz split-bf16 MFMA GEMM ----------
// C = scale*(coef*Af32 - A@B), A given as row-major splits (Ah,Al),
// B given as transposed splits (BTh,BTl = B^T row-major).
// Outputs optional: f32, normal splits, transposed splits.
template<bool HASCOEF, bool WF, bool WN, bool WT>
__global__ __launch_bounds__(256) void ns_k(
    const ushort_t* __restrict__ Ah, const ushort_t* __restrict__ Al,
    const ushort_t* __restrict__ BTh, const ushort_t* __restrict__ BTl,
    const float* __restrict__ Af32, float coef, float scale,
    float* __restrict__ Cf, ushort_t* __restrict__ Ch, ushort_t* __restrict__ Cl,
    ushort_t* __restrict__ CTh, ushort_t* __restrict__ CTl){
  __shared__ __align__(16) ushort_t Ahs[128*72];
  __shared__ __align__(16) ushort_t Als[128*72];
  __shared__ __align__(16) ushort_t Bhs[64*72];
  __shared__ __align__(16) ushort_t Bls[64*72];
  int batch = blockIdx.z;
  size_t mo = (size_t)batch*M_*M_;
  int row0 = blockIdx.y*128, col0 = blockIdx.x*64;
  int t = threadIdx.x, lane = t & 63, wave = t >> 6;
  int l16 = lane & 15, quad = lane >> 4;
  int wm = wave*32;
  f32x4 acc[2][4];
  #pragma unroll
  for (int i=0;i<2;i++)
    #pragma unroll
    for (int j=0;j<4;j++) acc[i][j] = (f32x4){0.f,0.f,0.f,0.f};
  int sr = t >> 3, sc = (t & 7) * 8;
  for (int k0=0;k0<M_;k0+=64){
    __syncthreads();
    #pragma unroll
    for (int p=0;p<4;p++){
      int r = sr + p*32;
      *(uint4*)&Ahs[r*72 + sc] = *(const uint4*)&Ah[mo + (size_t)(row0+r)*M_ + k0 + sc];
      *(uint4*)&Als[r*72 + sc] = *(const uint4*)&Al[mo + (size_t)(row0+r)*M_ + k0 + sc];
    }
    #pragma unroll
    for (int p=0;p<2;p++){
      int r = sr + p*32;
      *(uint4*)&Bhs[r*72 + sc] = *(const uint4*)&BTh[mo + (size_t)(col0+r)*M_ + k0 + sc];
      *(uint4*)&Bls[r*72 + sc] = *(const uint4*)&BTl[mo + (size_t)(col0+r)*M_ + k0 + sc];
    }
    __syncthreads();
    s16x8 fah[2][2], fal[2][2], fbh[4][2], fbl[4][2];
    #pragma unroll
    for (int mt=0;mt<2;mt++)
      #pragma unroll
      for (int kk=0;kk<2;kk++){
        fah[mt][kk] = *(const s16x8*)&Ahs[(wm + mt*16 + l16)*72 + kk*32 + quad*8];
        fal[mt][kk] = *(const s16x8*)&Als[(wm + mt*16 + l16)*72 + kk*32 + quad*8];
      }
    #pragma unroll
    for (int nt=0;nt<4;nt++)
      #pragma unroll
      for (int kk=0;kk<2;kk++){
        fbh[nt][kk] = *(const s16x8*)&Bhs[(nt*16 + l16)*72 + kk*32 + quad*8];
        fbl[nt][kk] = *(const s16x8*)&Bls[(nt*16 + l16)*72 + kk*32 + quad*8];
      }
    #pragma unroll
    for (int mt=0;mt<2;mt++)
      #pragma unroll
      for (int nt=0;nt<4;nt++)
        #pragma unroll
        for (int kk=0;kk<2;kk++){
          acc[mt][nt] = __builtin_amdgcn_mfma_f32_16x16x32_bf16(fah[mt][kk], fbh[nt][kk], acc[mt][nt], 0,0,0);
          acc[mt][nt] = __builtin_amdgcn_mfma_f32_16x16x32_bf16(fah[mt][kk], fbl[nt][kk], acc[mt][nt], 0,0,0);
          acc[mt][nt] = __builtin_amdgcn_mfma_f32_16x16x32_bf16(fal[mt][kk], fbh[nt][kk], acc[mt][nt], 0,0,0);
        }
  }
  #pragma unroll
  for (int mt=0;mt<2;mt++){
    #pragma unroll
    for (int nt=0;nt<4;nt++){
      int rbase = row0 + wm + mt*16 + quad*4;
      int c = col0 + nt*16 + l16;
      ushort_t th[4], tl[4];
      #pragma unroll
      for (int reg=0;reg<4;reg++){
        float a = acc[mt][nt][reg];
        float base = HASCOEF ? coef*Af32[mo + (size_t)(rbase+reg)*M_ + c] : 0.f;
        float v = scale*(base - a);
        if (WF) Cf[mo + (size_t)(rbase+reg)*M_ + c] = v;
        ushort_t hh = f2bf(v);
        ushort_t ll = f2bf(v - bf2f(hh));
        if (WN){
          Ch[mo + (size_t)(rbase+reg)*M_ + c] = hh;
          Cl[mo + (size_t)(rbase+reg)*M_ + c] = ll;
        }
        th[reg] = hh; tl[reg] = ll;
      }
      if (WT){
        unsigned h01 = (unsigned)th[0] | ((unsigned)th[1]<<16);
        unsigned h23 = (unsigned)th[2] | ((unsigned)th[3]<<16);
        unsigned l01 = (unsigned)tl[0] | ((unsigned)tl[1]<<16);
        unsigned l23 = (unsigned)tl[2] | ((unsigned)tl[3]<<16);
        uint2 vh; vh.x = h01; vh.y = h23;
        uint2 vl; vl.x = l01; vl.y = l23;
        *(uint2*)&CTh[mo + (size_t)c*M_ + rbase] = vh;
        *(uint2*)&CTl[mo + (size_t)c*M_ + rbase] = vl;
      }
    }
  }
}

// ---------- fused MFMA attention (flash-style), 16 q-rows per block ----------
template<int NKEYS, bool SCATTER>
__global__ __launch_bounds__(256) void attn_k(const ushort_t* __restrict__ Q,
    const ushort_t* __restrict__ Kb, const ushort_t* __restrict__ VT,
    float* __restrict__ uout, ushort_t* __restrict__ ob, int nqrows){
  __shared__ __align__(16) ushort_t Qs[16*72];
  __shared__ __align__(16) ushort_t Ks[128*72];
  __shared__ __align__(16) ushort_t Vs[64*136];
  __shared__ __align__(16) ushort_t Pb[16*136];
  __shared__ float ps[16*132];
  __shared__ float m_s[16], l_s[16], al_s[16];
  int bh = blockIdx.y, i0 = blockIdx.x*16;
  int t = threadIdx.x, wave = t >> 6, lane = t & 63;
  int l16 = lane & 15, quad = lane >> 4;
  if (t < 128)
    *(uint4*)&Qs[(t>>3)*72 + (t&7)*8] =
      *(const uint4*)&Q[((size_t)bh*nqrows + i0 + (t>>3))*D_ + (t&7)*8];
  if (t < 16){ m_s[t] = -1e30f; l_s[t] = 0.f; }
  f32x4 oacc = (f32x4){0.f,0.f,0.f,0.f};
  __syncthreads();
  for (int j0=0;j0<NKEYS;j0+=128){
    __syncthreads();
    #pragma unroll
    for (int p=0;p<4;p++){
      int key = (t>>3) + p*32;
      *(uint4*)&Ks[key*72 + (t&7)*8] =
        *(const uint4*)&Kb[((size_t)bh*NKEYS + j0 + key)*D_ + (t&7)*8];
    }
    #pragma unroll
    for (int p=0;p<4;p++){
      int d = t>>2, k8 = (t&3)*8 + p*32;
      *(uint4*)&Vs[d*136 + k8] =
        *(const uint4*)&VT[((size_t)bh*D_ + d)*NKEYS + j0 + k8];
    }
    __syncthreads();
    s16x8 a0 = *(const s16x8*)&Qs[l16*72 + quad*8];
    s16x8 a1 = *(const s16x8*)&Qs[l16*72 + 32 + quad*8];
    #pragma unroll
    for (int nt=0;nt<2;nt++){
      int ktile = wave*2 + nt;
      s16x8 b0 = *(const s16x8*)&Ks[(ktile*16 + l16)*72 + quad*8];
      s16x8 b1 = *(const s16x8*)&Ks[(ktile*16 + l16)*72 + 32 + quad*8];
      f32x4 s = (f32x4){0.f,0.f,0.f,0.f};
      s = __builtin_amdgcn_mfma_f32_16x16x32_bf16(a0, b0, s, 0,0,0);
      s = __builtin_amdgcn_mfma_f32_16x16x32_bf16(a1, b1, s, 0,0,0);
      #pragma unroll
      for (int reg=0;reg<4;reg++)
        ps[(quad*4+reg)*132 + ktile*16 + l16] = s[reg];
    }
    __syncthreads();
    {
      int r2 = t >> 4, c = t & 15;
      float lm = -1e30f;
      #pragma unroll
      for (int s=0;s<8;s++) lm = fmaxf(lm, ps[r2*132 + c + s*16]);
      #pragma unroll
      for (int o=8;o;o>>=1) lm = fmaxf(lm, __shfl_down(lm,o,16));
      lm = __shfl(lm, 0, 16);
      float mold = m_s[r2];
      float mnew = fmaxf(mold, lm);
      float lsum = 0.f;
      #pragma unroll
      for (int s=0;s<8;s++){
        float p = expf(ps[r2*132 + c + s*16] - mnew);
        Pb[r2*136 + c + s*16] = f2bf(p);
        lsum += p;
      }
      #pragma unroll
      for (int o=8;o;o>>=1) lsum += __shfl_down(lsum,o,16);
      if (c==0){
        float al = expf(mold - mnew);
        al_s[r2] = al;
        l_s[r2] = l_s[r2]*al + lsum;
        m_s[r2] = mnew;
      }
    }
    __syncthreads();
    #pragma unroll
    for (int reg=0;reg<4;reg++) oacc[reg] *= al_s[quad*4+reg];
    #pragma unroll
    for (int ks=0;ks<4;ks++){
      s16x8 a = *(const s16x8*)&Pb[l16*136 + ks*32 + quad*8];
      s16x8 b = *(const s16x8*)&Vs[(wave*16 + l16)*136 + ks*32 + quad*8];
      oacc = __builtin_amdgcn_mfma_f32_16x16x32_bf16(a, b, oacc, 0,0,0);
    }
  }
  #pragma unroll
  for (int reg=0;reg<4;reg++){
    int row = quad*4 + reg;
    float val = oacc[reg] / l_s[row];
    if (!SCATTER){
      uout[((size_t)bh*nqrows + i0 + row)*D_ + wave*16 + l16] = val;
    } else {
      int n = i0 + row, b = bh >> 3, h = bh & 7;
      ob[((size_t)(b*N_ + n))*DIM_ + h*D_ + wave*16 + l16] = f2bf(val);
    }
  }
}

// ---------- w = z @ u (fp32) ----------
__global__ void zu_k(const float* __restrict__ z, const float* __restrict__ u,
                     float* __restrict__ w){
  int idx = blockIdx.x*256 + threadIdx.x;
  int d = idx & 63, i = (idx >> 6) & 255, bh = idx >> 14;
  const float* zr = z + ((size_t)bh*M_+i)*M_;
  const float* ub = u + (size_t)bh*M_*D_ + d;
  float acc = 0.f;
  for (int kk=0;kk<M_;kk++) acc += zr[kk]*ub[(size_t)kk*D_];
  w[idx] = acc;
}

// ---------- depthwise conv residual, register-tiled: ob += conv(v) ----------
// thread: 8 seq positions x 8 channels; block: 256 n x 64 d for one bh.
__global__ __launch_bounds__(256) void conv2_k(const ushort_t* __restrict__ v,
    const float* __restrict__ cw, ushort_t* __restrict__ ob){
  int bh = blockIdx.y;
  int h = bh & 7, b = bh >> 3;
  int t = threadIdx.x;
  int d8 = (t & 7) * 8;
  int nloc = t >> 3;                       // 0..31
  int n0 = blockIdx.x * 256 + nloc * 8;
  __shared__ float wsm[33];
  if (t < 33) wsm[t] = cw[h*33 + t];
  __syncthreads();
  float wr[33];
  #pragma unroll
  for (int i=0;i<33;i++) wr[i] = wsm[i];
  float acc[8][8];
  #pragma unroll
  for (int j=0;j<8;j++)
    #pragma unroll
    for (int dd=0;dd<8;dd++) acc[j][dd] = 0.f;
  const ushort_t* vbase = v + (size_t)bh*N_*D_;
  #pragma unroll
  for (int r=0;r<40;r++){
    int nn = n0 - 16 + r;
    float vals[8];
    if (nn >= 0 && nn < N_){
      uint4 raw = *(const uint4*)&vbase[(size_t)nn*D_ + d8];
      const ushort_t* pr = (const ushort_t*)&raw;
      #pragma unroll
      for (int dd=0;dd<8;dd++) vals[dd] = bf2f(pr[dd]);
    } else {
      #pragma unroll
      for (int dd=0;dd<8;dd++) vals[dd] = 0.f;
    }
    #pragma unroll
    for (int j=0;j<8;j++){
      int tap = r - j;
      if (tap >= 0 && tap <= 32){
        float wj = wr[tap];
        #pragma unroll
        for (int dd=0;dd<8;dd++) acc[j][dd] += wj * vals[dd];
      }
    }
  }
  #pragma unroll
  for (int j=0;j<8;j++){
    size_t oi = ((size_t)(b*N_ + n0 + j))*DIM_ + h*D_ + d8;
    uint4 cur = *(uint4*)&ob[oi];
    ushort_t* pc = (ushort_t*)&cur;
    #pragma unroll
    for (int dd=0;dd<8;dd++) pc[dd] = f2bf(bf2f(pc[dd]) + acc[j][dd]);
    *(uint4*)&ob[oi] = cur;
  }
}

extern "C" void kernel_launch(void* const* d_in, const int* in_sizes, int n_in,
                              void* d_out, int out_size, void* d_ws, size_t ws_size,
                              hipStream_t stream){
  (void)in_sizes; (void)n_in; (void)out_size; (void)ws_size;
  const float* x      = (const float*)d_in[0];
  const float* gamma  = (const float*)d_in[1];
  const float* beta   = (const float*)d_in[2];
  const float* w_qkv  = (const float*)d_in[3];
  const float* w_out  = (const float*)d_in[4];
  const float* b_out  = (const float*)d_in[5];
  const float* conv_w = (const float*)d_in[6];
  float* y = (float*)d_out;
  float* ws = (float*)d_ws;

  size_t off = 0;
  ushort_t* xnb   = (ushort_t*)(ws + off); off += 4194304;   // 8.39M bf16 (dead after qkv; reused for az)
  ushort_t* qb    = (ushort_t*)(ws + off); off += 4194304;
  ushort_t* kb    = (ushort_t*)(ws + off); off += 4194304;
  ushort_t* vb    = (ushort_t*)(ws + off); off += 4194304;
  ushort_t* vT    = (ushort_t*)(ws + off); off += 4194304;
  ushort_t* wqkvT = (ushort_t*)(ws + off); off += 393216;
  ushort_t* woutT = (ushort_t*)(ws + off); off += 131072;
  ushort_t* qlb   = (ushort_t*)(ws + off); off += 262144;
  ushort_t* klb   = (ushort_t*)(ws + off); off += 262144;
  ushort_t* wzT   = (ushort_t*)(ws + off); off += 262144;
  ushort_t* ob    = (ushort_t*)(ws + off); off += 4194304;
  ushort_t* a2h   = (ushort_t*)(ws + off); off += 1048576;
  ushort_t* a2l   = (ushort_t*)(ws + off); off += 1048576;
  ushort_t* z0h   = (ushort_t*)(ws + off); off += 1048576;
  ushort_t* z0l   = (ushort_t*)(ws + off); off += 1048576;
  ushort_t* z0Th  = (ushort_t*)(ws + off); off += 1048576;
  ushort_t* z0Tl  = (ushort_t*)(ws + off); off += 1048576;
  ushort_t* z1h   = (ushort_t*)(ws + off); off += 1048576;
  ushort_t* z1l   = (ushort_t*)(ws + off); off += 1048576;
  ushort_t* z1Th  = (ushort_t*)(ws + off); off += 1048576;
  ushort_t* z1Tl  = (ushort_t*)(ws + off); off += 1048576;
  ushort_t* t1Th  = (ushort_t*)(ws + off); off += 1048576;
  ushort_t* t1Tl  = (ushort_t*)(ws + off); off += 1048576;
  ushort_t* t2Th  = (ushort_t*)(ws + off); off += 1048576;
  ushort_t* t2Tl  = (ushort_t*)(ws + off); off += 1048576;
  float* ql  = ws + off;  off += 524288;
  float* kl  = ws + off;  off += 524288;
  float* a2f = ws + off;  off += 2097152;
  float* z0f = ws + off;  off += 2097152;
  float* z1f = ws + off;  off += 2097152;
  float* azf = ws + off;  off += 2097152;
  float* u   = ws + off;  off += 524288;
  float* wz  = ws + off;  off += 524288;
  float* cs  = ws + off;  off += 8192;
  float* rs  = ws + off;  off += 8192;
  float* scal = ws + off; off += 8;
  // az splits reuse the xnb region (xnb dead after gemm_qkv; az born later)
  ushort_t* azh  = xnb;
  ushort_t* azl  = xnb + 2097152;
  ushort_t* azTh = xnb + 2*2097152;
  ushort_t* azTl = xnb + 3*2097152;

  ln_k<<<16384,256,0,stream>>>(x, gamma, beta, xnb);
  twb_k<<<dim3(24,8,1),256,0,stream>>>(w_qkv, wqkvT, 512, 1536);
  twb_k<<<dim3(8,8,1),256,0,stream>>>(w_out, woutT, 512, 512);
  gemm_qkv_k<<<dim3(12,128),256,0,stream>>>(xnb, wqkvT, qb, kb, vb);
  tbb_k<<<dim3(1,64,32),256,0,stream>>>(vb, vT, 4096, 64);
  lmk_k<<<2048,256,0,stream>>>(qb, kb, ql, kl, qlb, klb);
  attn2_k<<<dim3(256,32),256,0,stream>>>(ql, kl, a2f, a2h, a2l);
  colrow_k<<<32,256,0,stream>>>(a2f, cs, rs);
  maxred_k<<<1,256,0,stream>>>(cs, rs, scal);
  initz2_k<<<dim3(4,4,32),256,0,stream>>>(a2f, scal, z0f, z0h, z0l, z0Th, z0Tl);

  float* zcf = z0f; ushort_t *zch = z0h, *zcl = z0l, *zcTh = z0Th, *zcTl = z0Tl;
  float* znf = z1f; ushort_t *znh = z1h, *znl = z1l, *znTh = z1Th, *znTl = z1Tl;
  dim3 nsg(4,2,32);
  for (int it=0; it<6; it++){
    // az = a2@z
    ns_k<false,true,true,true><<<nsg,256,0,stream>>>(a2h, a2l, zcTh, zcTl,
        (const float*)nullptr, 0.f, -1.f, azf, azh, azl, azTh, azTl);
    // t1 = 7az - az@az
    ns_k<true,false,false,true><<<nsg,256,0,stream>>>(azh, azl, azTh, azTl,
        azf, 7.f, 1.f, (float*)nullptr, (ushort_t*)nullptr, (ushort_t*)nullptr, t1Th, t1Tl);
    // t2 = 15az - az@t1
    ns_k<true,false,false,true><<<nsg,256,0,stream>>>(azh, azl, t1Th, t1Tl,
        azf, 15.f, 1.f, (float*)nullptr, (ushort_t*)nullptr, (ushort_t*)nullptr, t2Th, t2Tl);
    // z' = 0.25*(13z - z@t2)
    ns_k<true,true,true,true><<<nsg,256,0,stream>>>(zch, zcl, t2Th, t2Tl,
        zcf, 13.f, 0.25f, znf, znh, znl, znTh, znTl);
    { float* tf=zcf; zcf=znf; znf=tf; }
    { ushort_t* tp;
      tp=zch; zch=znh; znh=tp;  tp=zcl; zcl=znl; znl=tp;
      tp=zcTh; zcTh=znTh; znTh=tp;  tp=zcTl; zcTl=znTl; znTl=tp; }
  }

  attn_k<4096,false><<<dim3(16,32),256,0,stream>>>(qlb, kb, vT, u, (ushort_t*)nullptr, 256);
  zu_k<<<2048,256,0,stream>>>(zcf, u, wz);
  twb_k<<<dim3(1,4,32),256,0,stream>>>(wz, wzT, 256, 64);
  attn_k<256,true><<<dim3(256,32),256,0,stream>>>(qb, klb, wzT, (float*)nullptr, ob, 4096);
  conv2_k<<<dim3(16,32),256,0,stream>>>(vb, conv_w, ob);
  final_k<<<dim3(4,128),256,0,stream>>>(ob, woutT, b_out, x, y);
}

// Round 5
// 775.098 us; speedup vs baseline: 3.4638x; 1.2335x over previous
//
#include <hip/hip_runtime.h>
#include <math.h>

#define BH 32
#define N_ 4096
#define D_ 64
#define M_ 256
#define L_ 16
#define DIM_ 512
#define K3_ 1536

typedef __attribute__((ext_vector_type(4))) float f32x4;
typedef __attribute__((ext_vector_type(8))) short s16x8;
typedef unsigned short ushort_t;

__device__ inline ushort_t f2bf(float f){
  union{float f; unsigned u;} v; v.f = f;
  unsigned r = v.u + 0x7fffu + ((v.u >> 16) & 1u);
  return (ushort_t)(r >> 16);
}
__device__ inline float bf2f(ushort_t b){
  union{unsigned u; float f;} v; v.u = ((unsigned)b) << 16; return v.f;
}

// ---------- reduction helpers ----------
__device__ inline float wave_sum(float v){
  #pragma unroll
  for (int o=32;o;o>>=1) v += __shfl_down(v,o,64);
  return v;
}
__device__ inline float wave_max(float v){
  #pragma unroll
  for (int o=32;o;o>>=1) v = fmaxf(v,__shfl_down(v,o,64));
  return v;
}
__device__ inline float blk_sum256(float v, float* sm){
  v = wave_sum(v);
  int lane = threadIdx.x & 63, wid = threadIdx.x >> 6;
  if (lane==0) sm[wid]=v;
  __syncthreads();
  float r = sm[0]+sm[1]+sm[2]+sm[3];
  __syncthreads();
  return r;
}
__device__ inline float blk_max256(float v, float* sm){
  v = wave_max(v);
  int lane = threadIdx.x & 63, wid = threadIdx.x >> 6;
  if (lane==0) sm[wid]=v;
  __syncthreads();
  float r = fmaxf(fmaxf(sm[0],sm[1]),fmaxf(sm[2],sm[3]));
  __syncthreads();
  return r;
}

// ---------- 1. LayerNorm -> bf16 ----------
__global__ __launch_bounds__(256) void ln_k(const float* __restrict__ x,
    const float* __restrict__ g, const float* __restrict__ bt, ushort_t* __restrict__ xn){
  int row = blockIdx.x, t = threadIdx.x;
  __shared__ float sm[4];
  const float* xr = x + (size_t)row*DIM_;
  float v0 = xr[t], v1 = xr[t+256];
  float mu = blk_sum256(v0+v1, sm) * (1.f/DIM_);
  float d0 = v0-mu, d1 = v1-mu;
  float var = blk_sum256(d0*d0+d1*d1, sm) * (1.f/DIM_);
  float rs = rsqrtf(var + 1e-5f);
  ushort_t* xo = xn + (size_t)row*DIM_;
  xo[t]     = f2bf(d0*rs*g[t]     + bt[t]);
  xo[t+256] = f2bf(d1*rs*g[t+256] + bt[t+256]);
}

// ---------- transpose fp32 [R][C] -> bf16 [C][R], batched via z ----------
__global__ __launch_bounds__(256) void twb_k(const float* __restrict__ src,
    ushort_t* __restrict__ dst, int R, int C){
  __shared__ ushort_t tile[64][66];
  size_t boff = (size_t)blockIdx.z * R * C;
  int r0 = blockIdx.y*64, c0 = blockIdx.x*64;
  int t = threadIdx.x, c = t & 63, r4 = t >> 6;
  #pragma unroll
  for (int i=0;i<16;i++){
    int rr = r4 + i*4;
    tile[c][rr] = f2bf(src[boff + (size_t)(r0+rr)*C + (c0+c)]);
  }
  __syncthreads();
  #pragma unroll
  for (int i=0;i<16;i++){
    int cc = r4 + i*4;
    dst[boff + (size_t)(c0+cc)*R + (r0 + c)] = tile[cc][c];
  }
}
// ---------- transpose bf16 [R][C] -> bf16 [C][R], batched ----------
__global__ __launch_bounds__(256) void tbb_k(const ushort_t* __restrict__ src,
    ushort_t* __restrict__ dst, int R, int C){
  __shared__ ushort_t tile[64][66];
  size_t boff = (size_t)blockIdx.z * R * C;
  int r0 = blockIdx.y*64, c0 = blockIdx.x*64;
  int t = threadIdx.x, c = t & 63, r4 = t >> 6;
  #pragma unroll
  for (int i=0;i<16;i++){
    int rr = r4 + i*4;
    tile[c][rr] = src[boff + (size_t)(r0+rr)*C + (c0+c)];
  }
  __syncthreads();
  #pragma unroll
  for (int i=0;i<16;i++){
    int cc = r4 + i*4;
    dst[boff + (size_t)(c0+cc)*R + (r0 + c)] = tile[cc][c];
  }
}

// ---------- 2. QKV GEMM bf16 MFMA ----------
__global__ __launch_bounds__(256) void gemm_qkv_k(const ushort_t* __restrict__ A,
    const ushort_t* __restrict__ Bt, ushort_t* __restrict__ qb, ushort_t* __restrict__ kb,
    ushort_t* __restrict__ vb){
  __shared__ __align__(16) ushort_t As[128*72];
  __shared__ __align__(16) ushort_t Bs[128*72];
  int t = threadIdx.x;
  int lane = t & 63, wave = t >> 6;
  int l16 = lane & 15, quad = lane >> 4;
  int wm = (wave & 1) * 64, wn = (wave >> 1) * 64;
  int row0 = blockIdx.y * 128, col0 = blockIdx.x * 128;
  f32x4 acc[4][4];
  #pragma unroll
  for (int i=0;i<4;i++)
    #pragma unroll
    for (int j=0;j<4;j++) acc[i][j] = (f32x4){0.f,0.f,0.f,0.f};
  int sr = t >> 3, sc = (t & 7) * 8;
  for (int k0=0;k0<DIM_;k0+=64){
    __syncthreads();
    #pragma unroll
    for (int p=0;p<4;p++){
      int r = sr + p*32;
      *(uint4*)&As[r*72 + sc] = *(const uint4*)&A[(size_t)(row0+r)*DIM_ + k0 + sc];
      *(uint4*)&Bs[r*72 + sc] = *(const uint4*)&Bt[(size_t)(col0+r)*DIM_ + k0 + sc];
    }
    __syncthreads();
    s16x8 af[4][2], bf[4][2];
    #pragma unroll
    for (int mt=0;mt<4;mt++)
      #pragma unroll
      for (int kk=0;kk<2;kk++)
        af[mt][kk] = *(const s16x8*)&As[(wm + mt*16 + l16)*72 + kk*32 + quad*8];
    #pragma unroll
    for (int nt=0;nt<4;nt++)
      #pragma unroll
      for (int kk=0;kk<2;kk++)
        bf[nt][kk] = *(const s16x8*)&Bs[(wn + nt*16 + l16)*72 + kk*32 + quad*8];
    #pragma unroll
    for (int mt=0;mt<4;mt++)
      #pragma unroll
      for (int nt=0;nt<4;nt++)
        #pragma unroll
        for (int kk=0;kk<2;kk++)
          acc[mt][nt] = __builtin_amdgcn_mfma_f32_16x16x32_bf16(af[mt][kk], bf[nt][kk], acc[mt][nt], 0,0,0);
  }
  #pragma unroll
  for (int mt=0;mt<4;mt++){
    #pragma unroll
    for (int nt=0;nt<4;nt++){
      #pragma unroll
      for (int reg=0;reg<4;reg++){
        int row = row0 + wm + mt*16 + quad*4 + reg;
        int col = col0 + wn + nt*16 + l16;
        float val = acc[mt][nt][reg];
        int b = row >> 12, n = row & 4095;
        int which = col >> 9, rem = col & 511;
        int h = rem >> 6, d = rem & 63;
        size_t dst = ((size_t)((b<<3)+h)*N_ + n)*D_ + d;
        if (which==0)      qb[dst] = f2bf(val*0.125f);
        else if (which==1) kb[dst] = f2bf(val);
        else               vb[dst] = f2bf(val);
      }
    }
  }
}

// ---------- final GEMM bf16 MFMA ----------
__global__ __launch_bounds__(256) void final_k(const ushort_t* __restrict__ A,
    const ushort_t* __restrict__ Bt, const float* __restrict__ bo,
    const float* __restrict__ x, float* __restrict__ y){
  __shared__ __align__(16) ushort_t As[128*72];
  __shared__ __align__(16) ushort_t Bs[128*72];
  int t = threadIdx.x;
  int lane = t & 63, wave = t >> 6;
  int l16 = lane & 15, quad = lane >> 4;
  int wm = (wave & 1) * 64, wn = (wave >> 1) * 64;
  int row0 = blockIdx.y * 128, col0 = blockIdx.x * 128;
  f32x4 acc[4][4];
  #pragma unroll
  for (int i=0;i<4;i++)
    #pragma unroll
    for (int j=0;j<4;j++) acc[i][j] = (f32x4){0.f,0.f,0.f,0.f};
  int sr = t >> 3, sc = (t & 7) * 8;
  for (int k0=0;k0<DIM_;k0+=64){
    __syncthreads();
    #pragma unroll
    for (int p=0;p<4;p++){
      int r = sr + p*32;
      *(uint4*)&As[r*72 + sc] = *(const uint4*)&A[(size_t)(row0+r)*DIM_ + k0 + sc];
      *(uint4*)&Bs[r*72 + sc] = *(const uint4*)&Bt[(size_t)(col0+r)*DIM_ + k0 + sc];
    }
    __syncthreads();
    s16x8 af[4][2], bf[4][2];
    #pragma unroll
    for (int mt=0;mt<4;mt++)
      #pragma unroll
      for (int kk=0;kk<2;kk++)
        af[mt][kk] = *(const s16x8*)&As[(wm + mt*16 + l16)*72 + kk*32 + quad*8];
    #pragma unroll
    for (int nt=0;nt<4;nt++)
      #pragma unroll
      for (int kk=0;kk<2;kk++)
        bf[nt][kk] = *(const s16x8*)&Bs[(wn + nt*16 + l16)*72 + kk*32 + quad*8];
    #pragma unroll
    for (int mt=0;mt<4;mt++)
      #pragma unroll
      for (int nt=0;nt<4;nt++)
        #pragma unroll
        for (int kk=0;kk<2;kk++)
          acc[mt][nt] = __builtin_amdgcn_mfma_f32_16x16x32_bf16(af[mt][kk], bf[nt][kk], acc[mt][nt], 0,0,0);
  }
  #pragma unroll
  for (int mt=0;mt<4;mt++){
    #pragma unroll
    for (int nt=0;nt<4;nt++){
      #pragma unroll
      for (int reg=0;reg<4;reg++){
        int row = row0 + wm + mt*16 + quad*4 + reg;
        int col = col0 + wn + nt*16 + l16;
        size_t o = (size_t)row*DIM_ + col;
        y[o] = acc[mt][nt][reg] + bo[col] + x[o];
      }
    }
  }
}

// ---------- 3. landmark means ----------
__global__ void lmk_k(const ushort_t* __restrict__ q, const ushort_t* __restrict__ k,
                      float* __restrict__ ql, float* __restrict__ kl,
                      ushort_t* __restrict__ qlb, ushort_t* __restrict__ klb){
  int idx = blockIdx.x*256 + threadIdx.x;
  int d = idx & 63, i = (idx >> 6) & 255, bh = idx >> 14;
  size_t base = ((size_t)bh*N_ + i*L_)*D_ + d;
  float sq=0.f, sk=0.f;
  #pragma unroll
  for (int tt=0;tt<L_;tt++){ sq += bf2f(q[base + (size_t)tt*D_]); sk += bf2f(k[base + (size_t)tt*D_]); }
  sq *= (1.f/L_); sk *= (1.f/L_);
  ql[idx] = sq; kl[idx] = sk;
  qlb[idx] = f2bf(sq); klb[idx] = f2bf(sk);
}

// ---------- 4. attn2 = softmax(ql @ kl^T)  -> fp32 + bf16 splits ----------
__global__ __launch_bounds__(256) void attn2_k(const float* __restrict__ ql,
    const float* __restrict__ kl, float* __restrict__ a2,
    ushort_t* __restrict__ a2h, ushort_t* __restrict__ a2l){
  int i = blockIdx.x, bh = blockIdx.y, t = threadIdx.x;
  __shared__ float qrow[64];
  __shared__ float sm[4];
  if (t < 64) qrow[t] = ql[((size_t)bh*M_+i)*D_ + t];
  __syncthreads();
  const float* kr = kl + ((size_t)bh*M_+t)*D_;
  float s = 0.f;
  #pragma unroll
  for (int d=0;d<64;d++) s += qrow[d]*kr[d];
  float mx = blk_max256(s, sm);
  float e = expf(s - mx);
  float den = blk_sum256(e, sm);
  float p = e/den;
  size_t idx = ((size_t)bh*M_+i)*M_ + t;
  a2[idx] = p;
  ushort_t hh = f2bf(p);
  a2h[idx] = hh;
  a2l[idx] = f2bf(p - bf2f(hh));
}

// ---------- pinv init ----------
__global__ void colrow_k(const float* __restrict__ a2, float* __restrict__ cs,
                         float* __restrict__ rs){
  int idx = blockIdx.x*256 + threadIdx.x;
  int j = idx & 255, bh = idx >> 8;
  const float* base = a2 + (size_t)bh*M_*M_;
  float c=0.f;
  for (int i=0;i<M_;i++)  c += fabsf(base[(size_t)i*M_ + j]);
  float r=0.f;
  const float4* rowp = (const float4*)(base + (size_t)j*M_);
  for (int q=0;q<M_/4;q++){
    float4 v = rowp[q];
    r += fabsf(v.x)+fabsf(v.y)+fabsf(v.z)+fabsf(v.w);
  }
  cs[idx]=c; rs[idx]=r;
}
__global__ __launch_bounds__(256) void maxred_k(const float* __restrict__ cs,
    const float* __restrict__ rs, float* __restrict__ scal){
  __shared__ float sm[4];
  float cm=-1e30f, rm=-1e30f;
  for (int i=threadIdx.x;i<BH*M_;i+=256){ cm=fmaxf(cm,cs[i]); rm=fmaxf(rm,rs[i]); }
  cm = blk_max256(cm, sm);
  rm = blk_max256(rm, sm);
  if (threadIdx.x==0) scal[0] = 1.f/(cm*rm);
}

// ---------- initz: z0 = scal*a2^T -> f32 + splits + transposed splits ----------
__global__ __launch_bounds__(256) void initz2_k(const float* __restrict__ a2,
    const float* __restrict__ scal, float* __restrict__ zf,
    ushort_t* __restrict__ zh, ushort_t* __restrict__ zl,
    ushort_t* __restrict__ zTh, ushort_t* __restrict__ zTl){
  __shared__ float tile[64][65];
  int bh = blockIdx.z;
  size_t mo = (size_t)bh*M_*M_;
  float s = scal[0];
  int r0 = blockIdx.y*64, c0 = blockIdx.x*64;
  int t = threadIdx.x, c = t & 63, r4 = t >> 6;
  #pragma unroll
  for (int i=0;i<16;i++){
    int rr = r4 + i*4;
    float v = a2[mo + (size_t)(r0+rr)*M_ + c0 + c] * s;
    tile[rr][c] = v;
    ushort_t hh = f2bf(v);
    size_t oi = mo + (size_t)(r0+rr)*M_ + c0 + c;
    zTh[oi] = hh;
    zTl[oi] = f2bf(v - bf2f(hh));
  }
  __syncthreads();
  #pragma unroll
  for (int i=0;i<16;i++){
    int zr = r4 + i*4;
    float v = tile[c][zr];
    size_t oi = mo + (size_t)(c0+zr)*M_ + r0 + c;
    zf[oi] = v;
    ushort_t hh = f2bf(v);
    zh[oi] = hh;
    zl[oi] = f2bf(v - bf2f(hh));
  }
}

// ---------- Newton-Schulz split-bf16 MFMA GEMM, 64x64 tiles ----------
template<bool HASCOEF, bool WF, bool WN, bool WT>
__global__ __launch_bounds__(256) void ns_k(
    const ushort_t* __restrict__ Ah, const ushort_t* __restrict__ Al,
    const ushort_t* __restrict__ BTh, const ushort_t* __restrict__ BTl,
    const float* __restrict__ Af32, float coef, float scale,
    float* __restrict__ Cf, ushort_t* __restrict__ Ch, ushort_t* __restrict__ Cl,
    ushort_t* __restrict__ CTh, ushort_t* __restrict__ CTl){
  __shared__ __align__(16) ushort_t Ahs[64*72];
  __shared__ __align__(16) ushort_t Als[64*72];
  __shared__ __align__(16) ushort_t Bhs[64*72];
  __shared__ __align__(16) ushort_t Bls[64*72];
  int batch = blockIdx.z;
  size_t mo = (size_t)batch*M_*M_;
  int row0 = blockIdx.y*64, col0 = blockIdx.x*64;
  int t = threadIdx.x, lane = t & 63, wave = t >> 6;
  int l16 = lane & 15, quad = lane >> 4;
  f32x4 acc[4];
  #pragma unroll
  for (int j=0;j<4;j++) acc[j] = (f32x4){0.f,0.f,0.f,0.f};
  int sr = t >> 3, sc = (t & 7) * 8;
  for (int k0=0;k0<M_;k0+=64){
    __syncthreads();
    #pragma unroll
    for (int p=0;p<2;p++){
      int r = sr + p*32;
      *(uint4*)&Ahs[r*72 + sc] = *(const uint4*)&Ah[mo + (size_t)(row0+r)*M_ + k0 + sc];
      *(uint4*)&Als[r*72 + sc] = *(const uint4*)&Al[mo + (size_t)(row0+r)*M_ + k0 + sc];
      *(uint4*)&Bhs[r*72 + sc] = *(const uint4*)&BTh[mo + (size_t)(col0+r)*M_ + k0 + sc];
      *(uint4*)&Bls[r*72 + sc] = *(const uint4*)&BTl[mo + (size_t)(col0+r)*M_ + k0 + sc];
    }
    __syncthreads();
    s16x8 fah[2], fal[2];
    #pragma unroll
    for (int kk=0;kk<2;kk++){
      fah[kk] = *(const s16x8*)&Ahs[(wave*16 + l16)*72 + kk*32 + quad*8];
      fal[kk] = *(const s16x8*)&Als[(wave*16 + l16)*72 + kk*32 + quad*8];
    }
    #pragma unroll
    for (int nt=0;nt<4;nt++){
      #pragma unroll
      for (int kk=0;kk<2;kk++){
        s16x8 fbh = *(const s16x8*)&Bhs[(nt*16 + l16)*72 + kk*32 + quad*8];
        s16x8 fbl = *(const s16x8*)&Bls[(nt*16 + l16)*72 + kk*32 + quad*8];
        acc[nt] = __builtin_amdgcn_mfma_f32_16x16x32_bf16(fah[kk], fbh, acc[nt], 0,0,0);
        acc[nt] = __builtin_amdgcn_mfma_f32_16x16x32_bf16(fah[kk], fbl, acc[nt], 0,0,0);
        acc[nt] = __builtin_amdgcn_mfma_f32_16x16x32_bf16(fal[kk], fbh, acc[nt], 0,0,0);
      }
    }
  }
  #pragma unroll
  for (int nt=0;nt<4;nt++){
    int rbase = row0 + wave*16 + quad*4;
    int c = col0 + nt*16 + l16;
    ushort_t th[4], tl[4];
    #pragma unroll
    for (int reg=0;reg<4;reg++){
      float a = acc[nt][reg];
      float base = HASCOEF ? coef*Af32[mo + (size_t)(rbase+reg)*M_ + c] : 0.f;
      float v = scale*(base - a);
      if (WF) Cf[mo + (size_t)(rbase+reg)*M_ + c] = v;
      ushort_t hh = f2bf(v);
      ushort_t ll = f2bf(v - bf2f(hh));
      if (WN){
        Ch[mo + (size_t)(rbase+reg)*M_ + c] = hh;
        Cl[mo + (size_t)(rbase+reg)*M_ + c] = ll;
      }
      th[reg] = hh; tl[reg] = ll;
    }
    if (WT){
      uint2 vh; vh.x = (unsigned)th[0] | ((unsigned)th[1]<<16); vh.y = (unsigned)th[2] | ((unsigned)th[3]<<16);
      uint2 vl; vl.x = (unsigned)tl[0] | ((unsigned)tl[1]<<16); vl.y = (unsigned)tl[2] | ((unsigned)tl[3]<<16);
      *(uint2*)&CTh[mo + (size_t)c*M_ + rbase] = vh;
      *(uint2*)&CTl[mo + (size_t)c*M_ + rbase] = vl;
    }
  }
}

// ---------- per-wave-full-row flash attention: 64 q-rows/block ----------
// Q[bh][nq][64], K[bh][nk][64], VT[bh][64][nk] bf16.
// SCATTER: normalize + scatter bf16 to ob[B][N][512]. else: unnormalized fp32
// partial + (m,l) stats per (half,bh,row) for a later combine.
template<int ITERS, bool SCATTER>
__global__ __launch_bounds__(256) void attn5_k(const ushort_t* __restrict__ Q,
    const ushort_t* __restrict__ K, const ushort_t* __restrict__ VT,
    int nq, int nk,
    float* __restrict__ up, float* __restrict__ mst, float* __restrict__ lst,
    ushort_t* __restrict__ ob){
  __shared__ __align__(16) ushort_t Ks[128*72];
  __shared__ __align__(16) ushort_t Vs[64*136];
  __shared__ __align__(16) ushort_t Pb[4*16*136];
  int bh = blockIdx.z, qblk = blockIdx.x, half = blockIdx.y;
  int key0 = half * (ITERS*128);
  int t = threadIdx.x, wave = t >> 6, lane = t & 63;
  int l16 = lane & 15, quad = lane >> 4;
  size_t qbase = ((size_t)bh*nq + qblk*64 + wave*16 + l16)*D_;
  s16x8 qa0 = *(const s16x8*)&Q[qbase + quad*8];
  s16x8 qa1 = *(const s16x8*)&Q[qbase + 32 + quad*8];
  const ushort_t* Kb = K + (size_t)bh*nk*D_;
  const ushort_t* Vb = VT + (size_t)bh*D_*nk;
  ushort_t* Pw = &Pb[wave*16*136];
  float m_r[4], l_r[4];
  #pragma unroll
  for (int r=0;r<4;r++){ m_r[r] = -1e30f; l_r[r] = 0.f; }
  f32x4 oacc[4];
  #pragma unroll
  for (int d=0;d<4;d++) oacc[d] = (f32x4){0.f,0.f,0.f,0.f};
  for (int it=0; it<ITERS; it++){
    int j0 = key0 + it*128;
    __syncthreads();
    #pragma unroll
    for (int p=0;p<4;p++){
      int idx = t + p*256;
      int kr = idx >> 3, kc = (idx & 7)*8;
      *(uint4*)&Ks[kr*72 + kc] = *(const uint4*)&Kb[(size_t)(j0+kr)*D_ + kc];
      int vd = idx >> 4, vc = (idx & 15)*8;
      *(uint4*)&Vs[vd*136 + vc] = *(const uint4*)&Vb[(size_t)vd*nk + j0 + vc];
    }
    __syncthreads();
    // S = Q@K^T for this wave's 16 rows x 128 keys
    f32x4 s[8];
    #pragma unroll
    for (int kt=0;kt<8;kt++){
      s16x8 b0 = *(const s16x8*)&Ks[(kt*16 + l16)*72 + quad*8];
      s16x8 b1 = *(const s16x8*)&Ks[(kt*16 + l16)*72 + 32 + quad*8];
      f32x4 z = (f32x4){0.f,0.f,0.f,0.f};
      z = __builtin_amdgcn_mfma_f32_16x16x32_bf16(qa0, b0, z, 0,0,0);
      z = __builtin_amdgcn_mfma_f32_16x16x32_bf16(qa1, b1, z, 0,0,0);
      s[kt] = z;
    }
    // in-wave online softmax (rows = quad*4+reg, key lanes = l16 group)
    float alpha[4], lsum[4];
    #pragma unroll
    for (int r=0;r<4;r++){
      float mx = s[0][r];
      #pragma unroll
      for (int kt=1;kt<8;kt++) mx = fmaxf(mx, s[kt][r]);
      mx = fmaxf(mx, __shfl_xor(mx, 1));
      mx = fmaxf(mx, __shfl_xor(mx, 2));
      mx = fmaxf(mx, __shfl_xor(mx, 4));
      mx = fmaxf(mx, __shfl_xor(mx, 8));
      float mn = fmaxf(m_r[r], mx);
      alpha[r] = __expf(m_r[r] - mn);
      m_r[r] = mn;
      lsum[r] = 0.f;
    }
    #pragma unroll
    for (int kt=0;kt<8;kt++){
      #pragma unroll
      for (int r=0;r<4;r++){
        float p = __expf(s[kt][r] - m_r[r]);
        Pw[(quad*4+r)*136 + kt*16 + l16] = f2bf(p);
        lsum[r] += p;
      }
    }
    #pragma unroll
    for (int r=0;r<4;r++){
      float ls = lsum[r];
      ls += __shfl_xor(ls, 1);
      ls += __shfl_xor(ls, 2);
      ls += __shfl_xor(ls, 4);
      ls += __shfl_xor(ls, 8);
      l_r[r] = l_r[r]*alpha[r] + ls;
      #pragma unroll
      for (int d=0;d<4;d++) oacc[d][r] *= alpha[r];
    }
    // PV (Pw is wave-private; compiler inserts lgkm waits)
    #pragma unroll
    for (int ks=0;ks<4;ks++){
      s16x8 pa = *(const s16x8*)&Pw[l16*136 + ks*32 + quad*8];
      #pragma unroll
      for (int dt=0;dt<4;dt++){
        s16x8 vv = *(const s16x8*)&Vs[(dt*16 + l16)*136 + ks*32 + quad*8];
        oacc[dt] = __builtin_amdgcn_mfma_f32_16x16x32_bf16(pa, vv, oacc[dt], 0,0,0);
      }
    }
  }
  int rowbase = qblk*64 + wave*16 + quad*4;
  if (SCATTER){
    int b = bh >> 3, h = bh & 7;
    #pragma unroll
    for (int dt=0;dt<4;dt++){
      #pragma unroll
      for (int r=0;r<4;r++){
        int n = rowbase + r;
        ob[((size_t)(b*N_ + n))*DIM_ + h*D_ + dt*16 + l16] = f2bf(oacc[dt][r] / l_r[r]);
      }
    }
  } else {
    size_t pb = ((size_t)(half*BH + bh)*M_ + rowbase)*D_;
    #pragma unroll
    for (int dt=0;dt<4;dt++){
      #pragma unroll
      for (int r=0;r<4;r++)
        up[pb + (size_t)r*D_ + dt*16 + l16] = oacc[dt][r];
    }
    if (l16 == 0){
      #pragma unroll
      for (int r=0;r<4;r++){
        size_t si = (size_t)(half*BH + bh)*M_ + rowbase + r;
        mst[si] = m_r[r];
        lst[si] = l_r[r];
      }
    }
  }
}

// ---------- combine 4 key-split partials -> u fp32 ----------
__global__ __launch_bounds__(256) void comb_k(const float* __restrict__ up,
    const float* __restrict__ mst, const float* __restrict__ lst,
    float* __restrict__ u){
  int idx = blockIdx.x*256 + threadIdx.x;     // (bh*256+row)*64+d
  int d = idx & 63; int row = (idx >> 6) & 255; int bh = idx >> 14;
  float m = -1e30f;
  float mv[4];
  #pragma unroll
  for (int hfs=0;hfs<4;hfs++){
    mv[hfs] = mst[(size_t)(hfs*BH + bh)*M_ + row];
    m = fmaxf(m, mv[hfs]);
  }
  float num = 0.f, den = 0.f;
  #pragma unroll
  for (int hfs=0;hfs<4;hfs++){
    float w = __expf(mv[hfs] - m);
    size_t ri = (size_t)(hfs*BH + bh)*M_ + row;
    den += lst[ri] * w;
    num += up[ri*D_ + d] * w;
  }
  u[idx] = num / den;
}

// ---------- w = z @ u (fp32) ----------
__global__ void zu_k(const float* __restrict__ z, const float* __restrict__ u,
                     float* __restrict__ w){
  int idx = blockIdx.x*256 + threadIdx.x;
  int d = idx & 63, i = (idx >> 6) & 255, bh = idx >> 14;
  const float* zr = z + ((size_t)bh*M_+i)*M_;
  const float* ub = u + (size_t)bh*M_*D_ + d;
  float acc = 0.f;
  for (int kk=0;kk<M_;kk++) acc += zr[kk]*ub[(size_t)kk*D_];
  w[idx] = acc;
}

// ---------- depthwise conv residual, register-tiled ----------
__global__ __launch_bounds__(256) void conv2_k(const ushort_t* __restrict__ v,
    const float* __restrict__ cw, ushort_t* __restrict__ ob){
  int bh = blockIdx.y;
  int h = bh & 7, b = bh >> 3;
  int t = threadIdx.x;
  int d8 = (t & 7) * 8;
  int nloc = t >> 3;
  int n0 = blockIdx.x * 256 + nloc * 8;
  __shared__ float wsm[33];
  if (t < 33) wsm[t] = cw[h*33 + t];
  __syncthreads();
  float wr[33];
  #pragma unroll
  for (int i=0;i<33;i++) wr[i] = wsm[i];
  float acc[8][8];
  #pragma unroll
  for (int j=0;j<8;j++)
    #pragma unroll
    for (int dd=0;dd<8;dd++) acc[j][dd] = 0.f;
  const ushort_t* vbase = v + (size_t)bh*N_*D_;
  #pragma unroll
  for (int r=0;r<40;r++){
    int nn = n0 - 16 + r;
    float vals[8];
    if (nn >= 0 && nn < N_){
      uint4 raw = *(const uint4*)&vbase[(size_t)nn*D_ + d8];
      const ushort_t* pr = (const ushort_t*)&raw;
      #pragma unroll
      for (int dd=0;dd<8;dd++) vals[dd] = bf2f(pr[dd]);
    } else {
      #pragma unroll
      for (int dd=0;dd<8;dd++) vals[dd] = 0.f;
    }
    #pragma unroll
    for (int j=0;j<8;j++){
      int tap = r - j;
      if (tap >= 0 && tap <= 32){
        float wj = wr[tap];
        #pragma unroll
        for (int dd=0;dd<8;dd++) acc[j][dd] += wj * vals[dd];
      }
    }
  }
  #pragma unroll
  for (int j=0;j<8;j++){
    size_t oi = ((size_t)(b*N_ + n0 + j))*DIM_ + h*D_ + d8;
    uint4 cur = *(uint4*)&ob[oi];
    ushort_t* pc = (ushort_t*)&cur;
    #pragma unroll
    for (int dd=0;dd<8;dd++) pc[dd] = f2bf(bf2f(pc[dd]) + acc[j][dd]);
    *(uint4*)&ob[oi] = cur;
  }
}

extern "C" void kernel_launch(void* const* d_in, const int* in_sizes, int n_in,
                              void* d_out, int out_size, void* d_ws, size_t ws_size,
                              hipStream_t stream){
  (void)in_sizes; (void)n_in; (void)out_size; (void)ws_size;
  const float* x      = (const float*)d_in[0];
  const float* gamma  = (const float*)d_in[1];
  const float* beta   = (const float*)d_in[2];
  const float* w_qkv  = (const float*)d_in[3];
  const float* w_out  = (const float*)d_in[4];
  const float* b_out  = (const float*)d_in[5];
  const float* conv_w = (const float*)d_in[6];
  float* y = (float*)d_out;
  float* ws = (float*)d_ws;

  size_t off = 0;
  ushort_t* xnb   = (ushort_t*)(ws + off); off += 4194304;
  ushort_t* qb    = (ushort_t*)(ws + off); off += 4194304;
  ushort_t* kb    = (ushort_t*)(ws + off); off += 4194304;
  ushort_t* vb    = (ushort_t*)(ws + off); off += 4194304;
  ushort_t* vT    = (ushort_t*)(ws + off); off += 4194304;
  ushort_t* wqkvT = (ushort_t*)(ws + off); off += 393216;
  ushort_t* woutT = (ushort_t*)(ws + off); off += 131072;
  ushort_t* qlb   = (ushort_t*)(ws + off); off += 262144;
  ushort_t* klb   = (ushort_t*)(ws + off); off += 262144;
  ushort_t* wzT   = (ushort_t*)(ws + off); off += 262144;
  ushort_t* ob    = (ushort_t*)(ws + off); off += 4194304;
  ushort_t* a2h   = (ushort_t*)(ws + off); off += 1048576;
  ushort_t* a2l   = (ushort_t*)(ws + off); off += 1048576;
  ushort_t* z0h   = (ushort_t*)(ws + off); off += 1048576;
  ushort_t* z0l   = (ushort_t*)(ws + off); off += 1048576;
  ushort_t* z0Th  = (ushort_t*)(ws + off); off += 1048576;
  ushort_t* z0Tl  = (ushort_t*)(ws + off); off += 1048576;
  ushort_t* z1h   = (ushort_t*)(ws + off); off += 1048576;
  ushort_t* z1l   = (ushort_t*)(ws + off); off += 1048576;
  ushort_t* z1Th  = (ushort_t*)(ws + off); off += 1048576;
  ushort_t* z1Tl  = (ushort_t*)(ws + off); off += 1048576;
  ushort_t* t1Th  = (ushort_t*)(ws + off); off += 1048576;
  ushort_t* t1Tl  = (ushort_t*)(ws + off); off += 1048576;
  ushort_t* t2Th  = (ushort_t*)(ws + off); off += 1048576;
  ushort_t* t2Tl  = (ushort_t*)(ws + off); off += 1048576;
  float* ql  = ws + off;  off += 524288;
  float* kl  = ws + off;  off += 524288;
  float* a2f = ws + off;  off += 2097152;
  float* z0f = ws + off;  off += 2097152;
  float* z1f = ws + off;  off += 2097152;
  float* azf = ws + off;  off += 2097152;
  float* u   = ws + off;  off += 524288;
  float* wz  = ws + off;  off += 524288;
  float* up  = ws + off;  off += 2097152;   // 4*32*256*64
  float* mstat = ws + off; off += 32768;
  float* lstat = ws + off; off += 32768;
  float* cs  = ws + off;  off += 8192;
  float* rs  = ws + off;  off += 8192;
  float* scal = ws + off; off += 8;
  ushort_t* azh  = xnb;
  ushort_t* azl  = xnb + 2097152;
  ushort_t* azTh = xnb + 2*2097152;
  ushort_t* azTl = xnb + 3*2097152;

  ln_k<<<16384,256,0,stream>>>(x, gamma, beta, xnb);
  twb_k<<<dim3(24,8,1),256,0,stream>>>(w_qkv, wqkvT, 512, 1536);
  twb_k<<<dim3(8,8,1),256,0,stream>>>(w_out, woutT, 512, 512);
  gemm_qkv_k<<<dim3(12,128),256,0,stream>>>(xnb, wqkvT, qb, kb, vb);
  tbb_k<<<dim3(1,64,32),256,0,stream>>>(vb, vT, 4096, 64);
  lmk_k<<<2048,256,0,stream>>>(qb, kb, ql, kl, qlb, klb);
  attn2_k<<<dim3(256,32),256,0,stream>>>(ql, kl, a2f, a2h, a2l);
  colrow_k<<<32,256,0,stream>>>(a2f, cs, rs);
  maxred_k<<<1,256,0,stream>>>(cs, rs, scal);
  initz2_k<<<dim3(4,4,32),256,0,stream>>>(a2f, scal, z0f, z0h, z0l, z0Th, z0Tl);

  float* zcf = z0f; ushort_t *zch = z0h, *zcl = z0l, *zcTh = z0Th, *zcTl = z0Tl;
  float* znf = z1f; ushort_t *znh = z1h, *znl = z1l, *znTh = z1Th, *znTl = z1Tl;
  dim3 nsg(4,4,32);
  for (int it=0; it<6; it++){
    ns_k<false,true,true,true><<<nsg,256,0,stream>>>(a2h, a2l, zcTh, zcTl,
        (const float*)nullptr, 0.f, -1.f, azf, azh, azl, azTh, azTl);
    ns_k<true,false,false,true><<<nsg,256,0,stream>>>(azh, azl, azTh, azTl,
        azf, 7.f, 1.f, (float*)nullptr, (ushort_t*)nullptr, (ushort_t*)nullptr, t1Th, t1Tl);
    ns_k<true,false,false,true><<<nsg,256,0,stream>>>(azh, azl, t1Th, t1Tl,
        azf, 15.f, 1.f, (float*)nullptr, (ushort_t*)nullptr, (ushort_t*)nullptr, t2Th, t2Tl);
    ns_k<true,true,true,true><<<nsg,256,0,stream>>>(zch, zcl, t2Th, t2Tl,
        zcf, 13.f, 0.25f, znf, znh, znl, znTh, znTl);
    { float* tf=zcf; zcf=znf; znf=tf; }
    { ushort_t* tp;
      tp=zch; zch=znh; znh=tp;  tp=zcl; zcl=znl; znl=tp;
      tp=zcTh; zcTh=znTh; znTh=tp;  tp=zcTl; zcTl=znTl; znTl=tp; }
  }

  // attn3: u_raw = softmax(ql@k^T)@v, 4-way key split + combine
  attn5_k<8,false><<<dim3(4,4,32),256,0,stream>>>(qlb, kb, vT, M_, N_,
      up, mstat, lstat, (ushort_t*)nullptr);
  comb_k<<<2048,256,0,stream>>>(up, mstat, lstat, u);
  zu_k<<<2048,256,0,stream>>>(zcf, u, wz);
  twb_k<<<dim3(1,4,32),256,0,stream>>>(wz, wzT, 256, 64);
  // attn1: ob = softmax(q@kl^T)@wz, scatter bf16
  attn5_k<2,true><<<dim3(64,1,32),256,0,stream>>>(qb, klb, wzT, N_, M_,
      (float*)nullptr, (float*)nullptr, (float*)nullptr, ob);
  conv2_k<<<dim3(16,32),256,0,stream>>>(vb, conv_w, ob);
  final_k<<<dim3(4,128),256,0,stream>>>(ob, woutT, b_out, x, y);
}